// Round 13
// baseline (2048.735 us; speedup 1.0000x reference)
//
#include <hip/hip_runtime.h>
#include <hip/hip_bf16.h>
#include <cstdint>
#include <cstddef>

// ---- problem constants ----
#define BB    32
#define CC    384
#define NHH   12
#define HDD   32
#define WSS   7
#define HKK   8
#define NBB   2
#define HIDD  1536
#define NTT   50          // tokens per window (1 cls + 49 patch)
#define NWW   2048        // B*HK*HK windows
#define LDOUT 19200       // 50*384
#define N3    1152        // 3*C

typedef __attribute__((ext_vector_type(8))) short short8v;
typedef __attribute__((ext_vector_type(4))) float f32x4;

#if defined(__has_builtin)
#if __has_builtin(__builtin_amdgcn_global_load_lds)
#define HAS_GLDS 1
#endif
#endif
#ifndef HAS_GLDS
#define HAS_GLDS 0
#endif

// fast GELU (tanh form)
static __device__ __forceinline__ float gelu_f(float x) {
    float t = x * (0.7978845608028654f + 0.03567740814f * x * x);
    float e = __expf(2.0f * t);
    float th = 1.0f - 2.0f / (e + 1.0f);
    return 0.5f * x * (1.0f + th);
}

static __device__ __forceinline__ short bf16s(float x) {
    __hip_bfloat16 b = __float2bfloat16(x);
    return *(short*)&b;
}

static __device__ __forceinline__ float bf2f(short s) {
    union { unsigned int u; float f; } cv;
    cv.u = ((unsigned int)(unsigned short)s) << 16;
    return cv.f;
}

#if HAS_GLDS
static __device__ __forceinline__ void glds16(const short* g, short* l) {
    __builtin_amdgcn_global_load_lds(
        (const __attribute__((address_space(1))) unsigned int*)g,
        (__attribute__((address_space(3))) unsigned int*)l,
        16, 0, 0);
}
#endif

// XCD-aware decode: keep all nx column-blocks of one row-panel on ONE XCD.
static __device__ __forceinline__ void swz_decode(int L, int nx, int ny, int& bx, int& by) {
    if (ny & 7) {
        bx = L % nx; by = L / nx;
    } else {
        int r = L & 7, pos = L >> 3;
        bx = pos % nx;
        by = (pos / nx) * 8 + r;
    }
}

// ---------------- pack / unpack (fp32 <-> bf16 residual stream) ----------------
__global__ void pack_cls_kernel(const float* __restrict__ cls, __hip_bfloat16* __restrict__ out) {
    __shared__ float lds[64][65];
    int bid = blockIdx.x;
    int b = bid / 6, cc = bid % 6, c0 = cc * 64;
    int tid = threadIdx.x;
    for (int idx = tid; idx < 64 * 64; idx += 256) {
        int k = idx & 63, cl = idx >> 6;
        lds[cl][k] = cls[((size_t)b * CC + c0 + cl) * 64 + k];
    }
    __syncthreads();
    short* ob = (short*)out;
    for (int idx = tid; idx < 64 * 64; idx += 256) {
        int cl = idx & 63, k = idx >> 6;
        ob[(size_t)(b * 64 + k) * LDOUT + c0 + cl] = bf16s(lds[cl][k]);
    }
}

__global__ void pack_patch_kernel(const float* __restrict__ patch, __hip_bfloat16* __restrict__ out) {
    __shared__ float lds[64][57];
    int bid = blockIdx.x;
    int b = bid / 336, rem = bid % 336;
    int y = rem / 6, cc = rem % 6, c0 = cc * 64;
    int tid = threadIdx.x;
    for (int idx = tid; idx < 64 * 56; idx += 256) {
        int cl = idx / 56, x = idx % 56;
        lds[cl][x] = patch[(((size_t)b * CC + c0 + cl) * 56 + y) * 56 + x];
    }
    __syncthreads();
    int wsy = y % 7, hky = y / 7;
    short* ob = (short*)out;
    for (int idx = tid; idx < 64 * 56; idx += 256) {
        int cl = idx & 63, x = idx >> 6;
        int tok = 1 + wsy * 7 + (x % 7);
        int win = b * 64 + hky * 8 + (x / 7);
        ob[((size_t)win * NTT + tok) * CC + c0 + cl] = bf16s(lds[cl][x]);
    }
}

__global__ void unpack_cls_kernel(const __hip_bfloat16* __restrict__ out, float* __restrict__ cls_out) {
    __shared__ float lds[64][65];
    int bid = blockIdx.x;
    int b = bid / 6, cc = bid % 6, c0 = cc * 64;
    int tid = threadIdx.x;
    const short* ob = (const short*)out;
    for (int idx = tid; idx < 64 * 64; idx += 256) {
        int cl = idx & 63, k = idx >> 6;
        lds[cl][k] = bf2f(ob[(size_t)(b * 64 + k) * LDOUT + c0 + cl]);
    }
    __syncthreads();
    for (int idx = tid; idx < 64 * 64; idx += 256) {
        int k = idx & 63, cl = idx >> 6;
        cls_out[((size_t)b * CC + c0 + cl) * 64 + k] = lds[cl][k];
    }
}

__global__ void unpack_patch_kernel(const __hip_bfloat16* __restrict__ out, float* __restrict__ patch_out) {
    __shared__ float lds[64][57];
    int bid = blockIdx.x;
    int b = bid / 336, rem = bid % 336;
    int y = rem / 6, cc = rem % 6, c0 = cc * 64;
    int tid = threadIdx.x;
    int wsy = y % 7, hky = y / 7;
    const short* ob = (const short*)out;
    for (int idx = tid; idx < 64 * 56; idx += 256) {
        int cl = idx & 63, x = idx >> 6;
        int tok = 1 + wsy * 7 + (x % 7);
        int win = b * 64 + hky * 8 + (x / 7);
        lds[cl][x] = bf2f(ob[((size_t)win * NTT + tok) * CC + c0 + cl]);
    }
    __syncthreads();
    for (int idx = tid; idx < 64 * 56; idx += 256) {
        int cl = idx / 56, x = idx % 56;
        patch_out[((size_t)b * CC + c0 + cl) * 3136 + y * 56 + x] = lds[cl][x];
    }
}

// ---------------- fp32 -> bf16 weight conversion ----------------
__global__ void f2bf_kernel(const float* __restrict__ in, __hip_bfloat16* __restrict__ out, int n) {
    int i = (blockIdx.x * 256 + threadIdx.x) * 4;
    if (i + 3 < n) {
        float4 v = *(const float4*)(in + i);
        out[i + 0] = __float2bfloat16(v.x);
        out[i + 1] = __float2bfloat16(v.y);
        out[i + 2] = __float2bfloat16(v.z);
        out[i + 3] = __float2bfloat16(v.w);
    } else {
        for (; i < n; ++i) out[i] = __float2bfloat16(in[i]);
    }
}

// ---------------- rel-pos bias table, fragment-ordered: [12][64 r][16 lc][4 n] fp32 ----------------
__global__ void bias_precompute_kernel(const float* __restrict__ rp, float* __restrict__ biasT) {
    int h = blockIdx.x;
    for (int idx = threadIdx.x; idx < 4096; idx += 256) {
        int qt = idx >> 6, kt = idx & 63;
        float v = 0.f;
        if (qt >= 1 && qt < NTT && kt >= 1 && kt < NTT) {
            int qp = qt - 1, kp = kt - 1;
            int qy = qp / 7, qx = qp - qy * 7;
            int ky = kp / 7, kx = kp - ky * 7;
            int ridx = ((ky - qy + 16) % 13) * 13 + ((kx - qx + 16) % 13);
            v = rp[h * 169 + ridx];
        }
        biasT[h * 4096 + qt * 64 + (kt & 15) * 4 + (kt >> 4)] = v;
    }
}

// ---------------- LayerNorm (bf16 in) -> bf16 out ----------------
__global__ void ln_kernel(const __hip_bfloat16* __restrict__ x, int ldx,
                          const float* __restrict__ w, const float* __restrict__ b,
                          __hip_bfloat16* __restrict__ y, int ldy, int M) {
    int wave = threadIdx.x >> 6, lane = threadIdx.x & 63;
    int row = blockIdx.x * 4 + wave;
    if (row >= M) return;
    const ushort2* xr = (const ushort2*)((const short*)x + (size_t)row * ldx);
    float2 vals[3];
    float s = 0.f;
#pragma unroll
    for (int j = 0; j < 3; ++j) {
        ushort2 u = xr[lane + j * 64];
        vals[j].x = bf2f((short)u.x);
        vals[j].y = bf2f((short)u.y);
        s += vals[j].x + vals[j].y;
    }
#pragma unroll
    for (int off = 32; off > 0; off >>= 1) s += __shfl_xor(s, off);
    float mean = s * (1.0f / 384.0f);
    float vs = 0.f;
#pragma unroll
    for (int j = 0; j < 3; ++j) {
        float dx = vals[j].x - mean, dy = vals[j].y - mean;
        vs += dx * dx + dy * dy;
    }
#pragma unroll
    for (int off = 32; off > 0; off >>= 1) vs += __shfl_xor(vs, off);
    float inv = rsqrtf(vs * (1.0f / 384.0f) + 1e-6f);
    const float2* w2 = (const float2*)w;
    const float2* b2 = (const float2*)b;
    ushort* yr = (ushort*)y + (size_t)row * ldy;
#pragma unroll
    for (int j = 0; j < 3; ++j) {
        int c = lane + j * 64;
        float2 wv = w2[c], bv = b2[c];
        ushort2 o;
        o.x = (ushort)bf16s((vals[j].x - mean) * inv * wv.x + bv.x);
        o.y = (ushort)bf16s((vals[j].y - mean) * inv * wv.y + bv.y);
        *(ushort2*)(yr + c * 2) = o;
    }
}

// ---------------- bf16 MFMA GEMM v5: Y = A[M,K] @ W[N,K]^T ----------------
// 256x128 tile, 8 waves (4M x 2N), wave = 64x64, BK=64, 2-slot ring (96 KB,
// 1 block/CU). Half the barrier crossings of BK=32 (32 MFMA per barrier-pair).
// Both-sides XOR bank swizzle (rule #21): LDS[r][g16] = global[r][g16^(r&7)]
//   write: glds stages 8-row chunks; lane l -> row l>>3, src group (l&7)^(l>>3)
//   read:  k-group gk read at LDS group gk^(row&7); row&7 == lane&7 here.
// vmcnt ledger (6 glds/STAGE/wave, depth-1): stage t+1 -> 12 out; vmcnt(6)
// waits own tile-t 6 (FIFO); last tile vmcnt(0). Slot overwrite WAR: slot s
// rewritten at tile t+2's STAGE; its readers finished before barrier B(t) and
// all waves passed B(t) before t+1 issues. launch_bounds(512,2): cap 256 VGPR
// (R10 lesson: never under-budget the accumulator).
template <int BIAS, int GELU, int ACC>
__global__ __launch_bounds__(512, 2) void gemm_bf16_kernel(
    const __hip_bfloat16* __restrict__ A, int lda,
    const __hip_bfloat16* __restrict__ W,
    const float* __restrict__ bias,
    __hip_bfloat16* __restrict__ Yb, int ldyb,
    int M, int N, int K, int nx) {
    __shared__ __align__(16) union SMemU {
        struct { short As[2][256 * 64]; short Bs[2][128 * 64]; } st;  // 96 KB ring
        short obf[256][132];   // 67.6 KB bf16 output tile
    } sm;
    int tid = threadIdx.x;
    int lane = tid & 63;
    int wid = tid >> 6;               // 0..7
    int wr = wid >> 1, wc = wid & 1;  // wr: 64-row band (0..3), wc: 64-col band (0..1)
    int bx, by;
    swz_decode(blockIdx.x, nx, M >> 8, bx, by);
    int row0 = by * 256, col0 = bx * 128;

    // swizzled staging pointers: lane l covers row (l>>3) of each 8-row chunk,
    // fetching global 16B-group (l&7)^(l>>3) of the 128B row.
    int srow8 = lane >> 3;                      // 0..7
    int sgrp  = ((lane & 7) ^ srow8) * 8;       // swizzled source col (elements)
    const short* Ag = (const short*)A + (size_t)(row0 + wid * 32 + srow8) * lda + sgrp;
    const short* Wg = (const short*)W + (size_t)(col0 + wid * 16 + srow8) * K + sgrp;
    int ldsA = wid * 32 * 64;   // wave-uniform base (elements); HW adds lane*16B
    int ldsB = wid * 16 * 64;

#if HAS_GLDS
#define STAGE(buf, k0)                                                        \
    do {                                                                      \
        glds16(Ag + (k0),                &sm.st.As[buf][ldsA]);               \
        glds16(Ag + 8 * lda + (k0),      &sm.st.As[buf][ldsA + 8 * 64]);      \
        glds16(Ag + 16 * lda + (k0),     &sm.st.As[buf][ldsA + 16 * 64]);     \
        glds16(Ag + 24 * lda + (k0),     &sm.st.As[buf][ldsA + 24 * 64]);     \
        glds16(Wg + (k0),                &sm.st.Bs[buf][ldsB]);               \
        glds16(Wg + 8 * (size_t)K + (k0), &sm.st.Bs[buf][ldsB + 8 * 64]);     \
    } while (0)
#else
#define STAGE(buf, k0)                                                                     \
    do {                                                                                   \
        *(short8v*)(&sm.st.As[buf][ldsA] + lane * 8) = *(const short8v*)(Ag + (k0));       \
        *(short8v*)(&sm.st.As[buf][ldsA + 8 * 64] + lane * 8) = *(const short8v*)(Ag + 8 * lda + (k0)); \
        *(short8v*)(&sm.st.As[buf][ldsA + 16 * 64] + lane * 8) = *(const short8v*)(Ag + 16 * lda + (k0)); \
        *(short8v*)(&sm.st.As[buf][ldsA + 24 * 64] + lane * 8) = *(const short8v*)(Ag + 24 * lda + (k0)); \
        *(short8v*)(&sm.st.Bs[buf][ldsB] + lane * 8) = *(const short8v*)(Wg + (k0));       \
        *(short8v*)(&sm.st.Bs[buf][ldsB + 8 * 64] + lane * 8) = *(const short8v*)(Wg + 8 * (size_t)K + (k0)); \
    } while (0)
#endif

    f32x4 acc[4][4] = {};
    // fragment LDS offsets (elements), swizzle folded in:
    //   row = band*64 + f*16 + (lane&15); row&7 == lane&7
    //   k-group gk = (lane>>4) + kh*4  ->  LDS group gk^(lane&7)
    int swzk[2];
#pragma unroll
    for (int kh = 0; kh < 2; ++kh)
        swzk[kh] = ((((lane >> 4) + kh * 4) ^ (lane & 7)) * 8);
    int arow[4], brow[4];
#pragma unroll
    for (int f = 0; f < 4; ++f) {
        arow[f] = (wr * 64 + f * 16 + (lane & 15)) * 64;
        brow[f] = (wc * 64 + f * 16 + (lane & 15)) * 64;
    }

    int nt = K >> 6;   // BK=64: K in {384,1536} -> nt in {6,24}
#if HAS_GLDS
    STAGE(0, 0);
    int sc = 0;
    for (int t = 0; t < nt; ++t) {
        if (t + 1 < nt) {
            STAGE(sc ^ 1, (t + 1) << 6);
            asm volatile("s_waitcnt vmcnt(6)" ::: "memory");
        } else {
            asm volatile("s_waitcnt vmcnt(0)" ::: "memory");
        }
        __builtin_amdgcn_s_barrier();          // A: everyone's tile-t loads landed
        __builtin_amdgcn_sched_barrier(0);
#pragma unroll
        for (int kh = 0; kh < 2; ++kh) {
            short8v a[4], b[4];
#pragma unroll
            for (int m = 0; m < 4; ++m) a[m] = *(const short8v*)&sm.st.As[sc][arow[m] + swzk[kh]];
#pragma unroll
            for (int n = 0; n < 4; ++n) b[n] = *(const short8v*)&sm.st.Bs[sc][brow[n] + swzk[kh]];
            __builtin_amdgcn_s_setprio(1);
#pragma unroll
            for (int m = 0; m < 4; ++m)
#pragma unroll
                for (int n = 0; n < 4; ++n)
                    acc[m][n] = __builtin_amdgcn_mfma_f32_16x16x32_bf16(a[m], b[n], acc[m][n], 0, 0, 0);
            __builtin_amdgcn_s_setprio(0);
        }
        __builtin_amdgcn_sched_barrier(0);
        __builtin_amdgcn_s_barrier();          // B: all waves consumed tile t
        sc ^= 1;
    }
#else
    for (int t = 0; t < nt; ++t) {
        STAGE(0, t << 6);
        __syncthreads();
#pragma unroll
        for (int kh = 0; kh < 2; ++kh) {
            short8v a[4], b[4];
#pragma unroll
            for (int m = 0; m < 4; ++m) a[m] = *(const short8v*)&sm.st.As[0][arow[m] + swzk[kh]];
#pragma unroll
            for (int n = 0; n < 4; ++n) b[n] = *(const short8v*)&sm.st.Bs[0][brow[n] + swzk[kh]];
#pragma unroll
            for (int m = 0; m < 4; ++m)
#pragma unroll
                for (int n = 0; n < 4; ++n)
                    acc[m][n] = __builtin_amdgcn_mfma_f32_16x16x32_bf16(a[m], b[n], acc[m][n], 0, 0, 0);
        }
        __syncthreads();
    }
#endif
#undef STAGE

    // ---- epilogue: LDS-staged coalesced bf16 stores (ACC: RMW during store) ----
    __syncthreads();   // staging ring dead; overlay output buffer
    int lr = (lane >> 4) * 4;
    int lc = lane & 15;
#pragma unroll
    for (int n = 0; n < 4; ++n) {
        int c = wc * 64 + n * 16 + lc;
        float bv = BIAS ? bias[col0 + c] : 0.0f;
#pragma unroll
        for (int m = 0; m < 4; ++m) {
#pragma unroll
            for (int j = 0; j < 4; ++j) {
                float v = acc[m][n][j] + bv;
                if (GELU) v = gelu_f(v);
                sm.obf[wr * 64 + m * 16 + lr + j][c] = bf16s(v);
            }
        }
    }
    __syncthreads();
    short* yb = (short*)Yb + (size_t)row0 * ldyb + col0;
#pragma unroll
    for (int it = 0; it < 8; ++it) {
        int r = (tid >> 4) + it * 32;
        int c8 = (tid & 15) * 8;
        short8v v = *(const short8v*)&sm.obf[r][c8];
        short* yp = yb + (size_t)r * ldyb + c8;
        if (ACC) {
            short8v o = *(const short8v*)yp;
#pragma unroll
            for (int e = 0; e < 8; ++e) v[e] = bf16s(bf2f(v[e]) + bf2f(o[e]));
        }
        *(short8v*)yp = v;
    }
}

// ---------------- MFMA attention, barrier-free, XCD-swizzled ----------------
__global__ __launch_bounds__(256) void attn_mfma_kernel(
    const __hip_bfloat16* __restrict__ qkv,
    const float* __restrict__ biasT,
    __hip_bfloat16* __restrict__ o,
    int T, float scale, int nwin) {
    __shared__ __align__(16) short Vt[4][32][72];   // [wave][d][kt]  (V transposed)
    __shared__ __align__(16) short Pl[4][64][40];   // [wave][r][half-K cols]
    const int tid = threadIdx.x, lane = tid & 63, wv = tid >> 6;
    int p, hg;
    {
        int L = blockIdx.x;
        if (nwin & 7) { hg = L % 3; p = L / 3; }
        else { int r = L & 7, pos = L >> 3; hg = pos % 3; p = (pos / 3) * 8 + r; }
    }
    const int h = hg * 4 + wv;
    const short* q_base = (const short*)qkv + (size_t)p * T * N3;

    const int fr = lane & 15;
    const int fk = (lane >> 4) * 8;
    const int lg = lane >> 4;
    const int lc = lane & 15;

    short8v aq[4], bk[4];
#pragma unroll
    for (int m = 0; m < 4; ++m) {
        const short* qp = q_base + (size_t)(m * 16 + fr) * N3 + h * 32 + fk;
        aq[m] = *(const short8v*)qp;
        bk[m] = *(const short8v*)(qp + 384);
    }

    for (int ch = lane; ch < T * 4; ch += 64) {
        int t = ch >> 2, cq = ch & 3;
        short8v v8 = *(const short8v*)(q_base + (size_t)t * N3 + 768 + h * 32 + cq * 8);
#pragma unroll
        for (int e = 0; e < 8; ++e) Vt[wv][cq * 8 + e][t] = v8[e];
    }
    for (int idx = lane; idx < (64 - T) * 32; idx += 64) {
        int t = T + (idx >> 5), d = idx & 31;
        Vt[wv][d][t] = 0;
    }

    f32x4 acc[4][4] = {};
#pragma unroll
    for (int m = 0; m < 4; ++m)
#pragma unroll
        for (int n = 0; n < 4; ++n)
            acc[m][n] = __builtin_amdgcn_mfma_f32_16x16x32_bf16(aq[m], bk[n], acc[m][n], 0, 0, 0);

    const float* bh = biasT ? (biasT + (size_t)h * 4096) : nullptr;
    float p2[4][4], p3[4][4];
#pragma unroll
    for (int m = 0; m < 4; ++m) {
#pragma unroll
        for (int j = 0; j < 4; ++j) {
            int r = m * 16 + lg * 4 + j;
            float v[4];
            if (bh) {
                float4 bv4 = *(const float4*)(bh + r * 64 + lc * 4);
#pragma unroll
                for (int n = 0; n < 4; ++n) v[n] = acc[m][n][j] * scale + ((const float*)&bv4)[n];
            } else {
#pragma unroll
                for (int n = 0; n < 4; ++n) v[n] = acc[m][n][j] * scale;
            }
#pragma unroll
            for (int n = 0; n < 4; ++n)
                if (n * 16 + lc >= T) v[n] = -1e30f;
            float mx = fmaxf(fmaxf(v[0], v[1]), fmaxf(v[2], v[3]));
#pragma unroll
            for (int off = 1; off < 16; off <<= 1) mx = fmaxf(mx, __shfl_xor(mx, off));
            float s = 0.f;
#pragma unroll
            for (int n = 0; n < 4; ++n) { v[n] = __expf(v[n] - mx); s += v[n]; }
#pragma unroll
            for (int off = 1; off < 16; off <<= 1) s += __shfl_xor(s, off);
            float inv = 1.0f / s;
            Pl[wv][r][lc]      = bf16s(v[0] * inv);
            Pl[wv][r][16 + lc] = bf16s(v[1] * inv);
            p2[m][j] = v[2] * inv;
            p3[m][j] = v[3] * inv;
        }
    }

    f32x4 oacc[4][2] = {};
    {
        short8v ap[4], bv[2];
#pragma unroll
        for (int m = 0; m < 4; ++m) ap[m] = *(const short8v*)&Pl[wv][m * 16 + fr][fk];
#pragma unroll
        for (int n = 0; n < 2; ++n) bv[n] = *(const short8v*)&Vt[wv][n * 16 + fr][fk];
#pragma unroll
        for (int m = 0; m < 4; ++m)
#pragma unroll
            for (int n = 0; n < 2; ++n)
                oacc[m][n] = __builtin_amdgcn_mfma_f32_16x16x32_bf16(ap[m], bv[n], oacc[m][n], 0, 0, 0);
    }
#pragma unroll
    for (int m = 0; m < 4; ++m)
#pragma unroll
        for (int j = 0; j < 4; ++j) {
            int r = m * 16 + lg * 4 + j;
            Pl[wv][r][lc]      = bf16s(p2[m][j]);
            Pl[wv][r][16 + lc] = bf16s(p3[m][j]);
        }
    {
        short8v ap[4], bv[2];
#pragma unroll
        for (int m = 0; m < 4; ++m) ap[m] = *(const short8v*)&Pl[wv][m * 16 + fr][fk];
#pragma unroll
        for (int n = 0; n < 2; ++n) bv[n] = *(const short8v*)&Vt[wv][n * 16 + fr][32 + fk];
#pragma unroll
        for (int m = 0; m < 4; ++m)
#pragma unroll
            for (int n = 0; n < 2; ++n)
                oacc[m][n] = __builtin_amdgcn_mfma_f32_16x16x32_bf16(ap[m], bv[n], oacc[m][n], 0, 0, 0);
    }

    short* ob = (short*)o;
#pragma unroll
    for (int m = 0; m < 4; ++m)
#pragma unroll
        for (int j = 0; j < 4; ++j) {
            int r = m * 16 + lg * 4 + j;
            if (r < T) {
#pragma unroll
                for (int n = 0; n < 2; ++n)
                    ob[((size_t)p * T + r) * CC + h * 32 + n * 16 + lc] = bf16s(oacc[m][n][j]);
            }
        }
}

// ---------------- host ----------------
extern "C" void kernel_launch(void* const* d_in, const int* in_sizes, int n_in,
                              void* d_out, int out_size, void* d_ws, size_t ws_size,
                              hipStream_t stream) {
    const float* cls_in   = (const float*)d_in[0];
    const float* patch_in = (const float*)d_in[1];
    const float* qkv_w    = (const float*)d_in[2];
    const float* qkv_b    = (const float*)d_in[3];
    const float* proj_w   = (const float*)d_in[4];
    const float* proj_b   = (const float*)d_in[5];
    const float* rel_pos  = (const float*)d_in[6];
    const float* ln0w = (const float*)d_in[7];
    const float* ln0b = (const float*)d_in[8];
    const float* ln1w = (const float*)d_in[9];
    const float* ln1b = (const float*)d_in[10];
    const float* ln2w = (const float*)d_in[11];
    const float* ln2b = (const float*)d_in[12];
    const float* w1 = (const float*)d_in[13];
    const float* b1 = (const float*)d_in[14];
    const float* w2 = (const float*)d_in[15];
    const float* b2 = (const float*)d_in[16];

    float* WS = (float*)d_ws;
    size_t avail = ws_size / 4;

    // bf16 residual stream: 2048*50*384 bf16 = 19,660,800 f32 slots
    const size_t OUT_FB = 19660800;
    const size_t WB_F   = 1769472;           // bf16 weights (f32 slots)
    const size_t BT_F   = 49152;             // bias table 12*64*64 fp32
    __hip_bfloat16* OUTB = (__hip_bfloat16*)WS;
    __hip_bfloat16* WB = (__hip_bfloat16*)(WS + OUT_FB);
    __hip_bfloat16* qwb = WB;                                   // 2*1152*384
    __hip_bfloat16* pwb = WB + 884736;                          // 2*384*384
    __hip_bfloat16* w1b = WB + 1179648;                         // 2*1536*384
    __hip_bfloat16* w2b = WB + 2359296;                         // 2*384*1536
    float* biasTbuf = WS + OUT_FB + WB_F;

    // cw = 1024. cw*NTT must be a multiple of 256 (cw >= 128).
    int cw = 1024;
    while (cw > 128 && OUT_FB + WB_F + BT_F + (size_t)cw * 48000 > avail) cw >>= 1;
    float* fbase = WS + OUT_FB + WB_F + BT_F;
    __hip_bfloat16* Xb = (__hip_bfloat16*)fbase;
    __hip_bfloat16* Qb = (__hip_bfloat16*)(fbase + (size_t)cw * 9600);
    __hip_bfloat16* Hb = Qb;   // MLP hidden reuses Qb region
    const float scale = 0.17677669529663687f;

    f2bf_kernel<<<dim3((884736 / 4 + 255) / 256), dim3(256), 0, stream>>>(qkv_w, qwb, 884736);
    f2bf_kernel<<<dim3((294912 / 4 + 255) / 256), dim3(256), 0, stream>>>(proj_w, pwb, 294912);
    f2bf_kernel<<<dim3((1179648 / 4 + 255) / 256), dim3(256), 0, stream>>>(w1, w1b, 1179648);
    f2bf_kernel<<<dim3((1179648 / 4 + 255) / 256), dim3(256), 0, stream>>>(w2, w2b, 1179648);

    pack_cls_kernel<<<dim3(BB * 6), dim3(256), 0, stream>>>(cls_in, OUTB);
    pack_patch_kernel<<<dim3(BB * 56 * 6), dim3(256), 0, stream>>>(patch_in, OUTB);

    for (int i = 0; i < NBB; ++i) {
        const __hip_bfloat16* qw = qwb + (size_t)i * N3 * CC;
        const float* qb = qkv_b + (size_t)i * N3;
        const __hip_bfloat16* pw = pwb + (size_t)i * CC * CC;
        const float* pb = proj_b + (size_t)i * CC;
        const float* rp = rel_pos + (size_t)i * NHH * 169;
        const __hip_bfloat16* w1i = w1b + (size_t)i * HIDD * CC;
        const float* b1i = b1 + (size_t)i * HIDD;
        const __hip_bfloat16* w2i = w2b + (size_t)i * CC * HIDD;
        const float* b2i = b2 + (size_t)i * CC;

        bias_precompute_kernel<<<dim3(NHH), dim3(256), 0, stream>>>(rp, biasTbuf);

        // ---- stage A: cls attention across 64 windows of each image (T=64) ----
        ln_kernel<<<dim3(2048 / 4), dim3(256), 0, stream>>>(OUTB, LDOUT, ln0w + i * CC, ln0b + i * CC, Xb, CC, 2048);
        gemm_bf16_kernel<1, 0, 0><<<dim3((N3 / 128) * (2048 / 256)), dim3(512), 0, stream>>>(
            Xb, CC, qw, qb, Qb, N3, 2048, N3, CC, N3 / 128);
        attn_mfma_kernel<<<dim3(BB * 3), dim3(256), 0, stream>>>(Qb, nullptr, Xb, 64, scale, BB);
        gemm_bf16_kernel<1, 0, 1><<<dim3((CC / 128) * (2048 / 256)), dim3(512), 0, stream>>>(
            Xb, CC, pw, pb, OUTB, LDOUT, 2048, CC, CC, CC / 128);

        // ---- stage B: windowed attention with rel-pos bias (T=50) ----
        for (int w0 = 0; w0 < NWW; w0 += cw) {
            __hip_bfloat16* outc = OUTB + (size_t)w0 * LDOUT;
            int Mr = cw * NTT;
            ln_kernel<<<dim3(Mr / 4), dim3(256), 0, stream>>>(outc, CC, ln1w + i * CC, ln1b + i * CC, Xb, CC, Mr);
            gemm_bf16_kernel<1, 0, 0><<<dim3((N3 / 128) * (Mr / 256)), dim3(512), 0, stream>>>(
                Xb, CC, qw, qb, Qb, N3, Mr, N3, CC, N3 / 128);
            attn_mfma_kernel<<<dim3(cw * 3), dim3(256), 0, stream>>>(Qb, biasTbuf, Xb, NTT, scale, cw);
            gemm_bf16_kernel<1, 0, 1><<<dim3((CC / 128) * (Mr / 256)), dim3(512), 0, stream>>>(
                Xb, CC, pw, pb, outc, CC, Mr, CC, CC, CC / 128);
        }

        // ---- stage C: MLP ----
        for (int w0 = 0; w0 < NWW; w0 += cw) {
            __hip_bfloat16* outc = OUTB + (size_t)w0 * LDOUT;
            int Mr = cw * NTT;
            ln_kernel<<<dim3(Mr / 4), dim3(256), 0, stream>>>(outc, CC, ln2w + i * CC, ln2b + i * CC, Xb, CC, Mr);
            gemm_bf16_kernel<1, 1, 0><<<dim3((HIDD / 128) * (Mr / 256)), dim3(512), 0, stream>>>(
                Xb, CC, w1i, b1i, Hb, HIDD, Mr, HIDD, CC, HIDD / 128);
            gemm_bf16_kernel<1, 0, 1><<<dim3((CC / 128) * (Mr / 256)), dim3(512), 0, stream>>>(
                Hb, HIDD, w2i, b2i, outc, CC, Mr, CC, HIDD, CC / 128);
        }
    }

    unpack_cls_kernel<<<dim3(BB * 6), dim3(256), 0, stream>>>(OUTB, (float*)d_out);
    unpack_patch_kernel<<<dim3(BB * 56 * 6), dim3(256), 0, stream>>>(OUTB, (float*)d_out + 786432);
}

// Round 14
// 1869.650 us; speedup vs baseline: 1.0958x; 1.0958x over previous
//
#include <hip/hip_runtime.h>
#include <hip/hip_bf16.h>
#include <cstdint>
#include <cstddef>

// ---- problem constants ----
#define BB    32
#define CC    384
#define NHH   12
#define HDD   32
#define WSS   7
#define HKK   8
#define NBB   2
#define HIDD  1536
#define NTT   50          // tokens per window (1 cls + 49 patch)
#define NWW   2048        // B*HK*HK windows
#define LDOUT 19200       // 50*384
#define N3    1152        // 3*C

typedef __attribute__((ext_vector_type(8))) short short8v;
typedef __attribute__((ext_vector_type(4))) float f32x4;

#if defined(__has_builtin)
#if __has_builtin(__builtin_amdgcn_global_load_lds)
#define HAS_GLDS 1
#endif
#endif
#ifndef HAS_GLDS
#define HAS_GLDS 0
#endif

// fast GELU (tanh form)
static __device__ __forceinline__ float gelu_f(float x) {
    float t = x * (0.7978845608028654f + 0.03567740814f * x * x);
    float e = __expf(2.0f * t);
    float th = 1.0f - 2.0f / (e + 1.0f);
    return 0.5f * x * (1.0f + th);
}

static __device__ __forceinline__ short bf16s(float x) {
    __hip_bfloat16 b = __float2bfloat16(x);
    return *(short*)&b;
}

static __device__ __forceinline__ float bf2f(short s) {
    union { unsigned int u; float f; } cv;
    cv.u = ((unsigned int)(unsigned short)s) << 16;
    return cv.f;
}

#if HAS_GLDS
static __device__ __forceinline__ void glds16(const short* g, short* l) {
    __builtin_amdgcn_global_load_lds(
        (const __attribute__((address_space(1))) unsigned int*)g,
        (__attribute__((address_space(3))) unsigned int*)l,
        16, 0, 0);
}
#endif

// XCD-aware decode: keep all nx column-blocks of one row-panel on ONE XCD.
static __device__ __forceinline__ void swz_decode(int L, int nx, int ny, int& bx, int& by) {
    if (ny & 7) {
        bx = L % nx; by = L / nx;
    } else {
        int r = L & 7, pos = L >> 3;
        bx = pos % nx;
        by = (pos / nx) * 8 + r;
    }
}

// ---------------- pack / unpack (fp32 <-> bf16 residual stream) ----------------
__global__ void pack_cls_kernel(const float* __restrict__ cls, __hip_bfloat16* __restrict__ out) {
    __shared__ float lds[64][65];
    int bid = blockIdx.x;
    int b = bid / 6, cc = bid % 6, c0 = cc * 64;
    int tid = threadIdx.x;
    for (int idx = tid; idx < 64 * 64; idx += 256) {
        int k = idx & 63, cl = idx >> 6;
        lds[cl][k] = cls[((size_t)b * CC + c0 + cl) * 64 + k];
    }
    __syncthreads();
    short* ob = (short*)out;
    for (int idx = tid; idx < 64 * 64; idx += 256) {
        int cl = idx & 63, k = idx >> 6;
        ob[(size_t)(b * 64 + k) * LDOUT + c0 + cl] = bf16s(lds[cl][k]);
    }
}

__global__ void pack_patch_kernel(const float* __restrict__ patch, __hip_bfloat16* __restrict__ out) {
    __shared__ float lds[64][57];
    int bid = blockIdx.x;
    int b = bid / 336, rem = bid % 336;
    int y = rem / 6, cc = rem % 6, c0 = cc * 64;
    int tid = threadIdx.x;
    for (int idx = tid; idx < 64 * 56; idx += 256) {
        int cl = idx / 56, x = idx % 56;
        lds[cl][x] = patch[(((size_t)b * CC + c0 + cl) * 56 + y) * 56 + x];
    }
    __syncthreads();
    int wsy = y % 7, hky = y / 7;
    short* ob = (short*)out;
    for (int idx = tid; idx < 64 * 56; idx += 256) {
        int cl = idx & 63, x = idx >> 6;
        int tok = 1 + wsy * 7 + (x % 7);
        int win = b * 64 + hky * 8 + (x / 7);
        ob[((size_t)win * NTT + tok) * CC + c0 + cl] = bf16s(lds[cl][x]);
    }
}

__global__ void unpack_cls_kernel(const __hip_bfloat16* __restrict__ out, float* __restrict__ cls_out) {
    __shared__ float lds[64][65];
    int bid = blockIdx.x;
    int b = bid / 6, cc = bid % 6, c0 = cc * 64;
    int tid = threadIdx.x;
    const short* ob = (const short*)out;
    for (int idx = tid; idx < 64 * 64; idx += 256) {
        int cl = idx & 63, k = idx >> 6;
        lds[cl][k] = bf2f(ob[(size_t)(b * 64 + k) * LDOUT + c0 + cl]);
    }
    __syncthreads();
    for (int idx = tid; idx < 64 * 64; idx += 256) {
        int k = idx & 63, cl = idx >> 6;
        cls_out[((size_t)b * CC + c0 + cl) * 64 + k] = lds[cl][k];
    }
}

__global__ void unpack_patch_kernel(const __hip_bfloat16* __restrict__ out, float* __restrict__ patch_out) {
    __shared__ float lds[64][57];
    int bid = blockIdx.x;
    int b = bid / 336, rem = bid % 336;
    int y = rem / 6, cc = rem % 6, c0 = cc * 64;
    int tid = threadIdx.x;
    int wsy = y % 7, hky = y / 7;
    const short* ob = (const short*)out;
    for (int idx = tid; idx < 64 * 56; idx += 256) {
        int cl = idx & 63, x = idx >> 6;
        int tok = 1 + wsy * 7 + (x % 7);
        int win = b * 64 + hky * 8 + (x / 7);
        lds[cl][x] = bf2f(ob[((size_t)win * NTT + tok) * CC + c0 + cl]);
    }
    __syncthreads();
    for (int idx = tid; idx < 64 * 56; idx += 256) {
        int cl = idx / 56, x = idx % 56;
        patch_out[((size_t)b * CC + c0 + cl) * 3136 + y * 56 + x] = lds[cl][x];
    }
}

// ---------------- fp32 -> bf16 weight conversion ----------------
__global__ void f2bf_kernel(const float* __restrict__ in, __hip_bfloat16* __restrict__ out, int n) {
    int i = (blockIdx.x * 256 + threadIdx.x) * 4;
    if (i + 3 < n) {
        float4 v = *(const float4*)(in + i);
        out[i + 0] = __float2bfloat16(v.x);
        out[i + 1] = __float2bfloat16(v.y);
        out[i + 2] = __float2bfloat16(v.z);
        out[i + 3] = __float2bfloat16(v.w);
    } else {
        for (; i < n; ++i) out[i] = __float2bfloat16(in[i]);
    }
}

// ---------------- rel-pos bias table, fragment-ordered: [12][64 r][16 lc][4 n] fp32 ----------------
__global__ void bias_precompute_kernel(const float* __restrict__ rp, float* __restrict__ biasT) {
    int h = blockIdx.x;
    for (int idx = threadIdx.x; idx < 4096; idx += 256) {
        int qt = idx >> 6, kt = idx & 63;
        float v = 0.f;
        if (qt >= 1 && qt < NTT && kt >= 1 && kt < NTT) {
            int qp = qt - 1, kp = kt - 1;
            int qy = qp / 7, qx = qp - qy * 7;
            int ky = kp / 7, kx = kp - ky * 7;
            int ridx = ((ky - qy + 16) % 13) * 13 + ((kx - qx + 16) % 13);
            v = rp[h * 169 + ridx];
        }
        biasT[h * 4096 + qt * 64 + (kt & 15) * 4 + (kt >> 4)] = v;
    }
}

// ---------------- LayerNorm (bf16 in) -> bf16 out ----------------
__global__ void ln_kernel(const __hip_bfloat16* __restrict__ x, int ldx,
                          const float* __restrict__ w, const float* __restrict__ b,
                          __hip_bfloat16* __restrict__ y, int ldy, int M) {
    int wave = threadIdx.x >> 6, lane = threadIdx.x & 63;
    int row = blockIdx.x * 4 + wave;
    if (row >= M) return;
    const ushort2* xr = (const ushort2*)((const short*)x + (size_t)row * ldx);
    float2 vals[3];
    float s = 0.f;
#pragma unroll
    for (int j = 0; j < 3; ++j) {
        ushort2 u = xr[lane + j * 64];
        vals[j].x = bf2f((short)u.x);
        vals[j].y = bf2f((short)u.y);
        s += vals[j].x + vals[j].y;
    }
#pragma unroll
    for (int off = 32; off > 0; off >>= 1) s += __shfl_xor(s, off);
    float mean = s * (1.0f / 384.0f);
    float vs = 0.f;
#pragma unroll
    for (int j = 0; j < 3; ++j) {
        float dx = vals[j].x - mean, dy = vals[j].y - mean;
        vs += dx * dx + dy * dy;
    }
#pragma unroll
    for (int off = 32; off > 0; off >>= 1) vs += __shfl_xor(vs, off);
    float inv = rsqrtf(vs * (1.0f / 384.0f) + 1e-6f);
    const float2* w2 = (const float2*)w;
    const float2* b2 = (const float2*)b;
    ushort* yr = (ushort*)y + (size_t)row * ldy;
#pragma unroll
    for (int j = 0; j < 3; ++j) {
        int c = lane + j * 64;
        float2 wv = w2[c], bv = b2[c];
        ushort2 o;
        o.x = (ushort)bf16s((vals[j].x - mean) * inv * wv.x + bv.x);
        o.y = (ushort)bf16s((vals[j].y - mean) * inv * wv.y + bv.y);
        *(ushort2*)(yr + c * 2) = o;
    }
}

// ---------------- bf16 MFMA GEMM v6: Y = A[M,K] @ W[N,K]^T ----------------
// R12 structure (best measured): 256x128 tile, 8 waves (4M x 2N), BK=32,
// 3-slot ring (72 KB -> 2 blocks/CU), counted-vmcnt depth-2 (6/3/0).
// NEW: both-sides XOR bank swizzle (mechanism verified R13: conflicts 8.6M->1.2M):
//   LDS[r][g16] = global[r][g16 ^ ((r>>1)&3)]   (rows are 64B = 4 groups)
//   write: lane l stages row l>>2, LDS group l&3 -> source group (l&3)^((l>>3)&3)
//          (permutation within one 64B segment: global coalescing preserved)
//   read:  k-group gk = lane>>4 at row band+f*16+(lane&15) -> LDS group
//          gk ^ (((lane&15)>>1)&3); per-lane constant, folded into pointer.
//   result: each quarter-wave's 16 ds_read lanes spread over all 8 bank-quads
//   (2 lanes/bank = free per m136); unswizzled was 2 quads (4x serialization).
// launch_bounds(512,4) (R10 lesson: never under-budget the accumulator).
template <int BIAS, int GELU, int ACC>
__global__ __launch_bounds__(512, 4) void gemm_bf16_kernel(
    const __hip_bfloat16* __restrict__ A, int lda,
    const __hip_bfloat16* __restrict__ W,
    const float* __restrict__ bias,
    __hip_bfloat16* __restrict__ Yb, int ldyb,
    int M, int N, int K, int nx) {
    __shared__ __align__(16) union SMemU {
        struct { short As[3][256 * 32]; short Bs[3][128 * 32]; } st;  // 72 KB ring
        short obf[256][132];   // 67.6 KB bf16 output tile
    } sm;
    int tid = threadIdx.x;
    int lane = tid & 63;
    int wid = tid >> 6;               // 0..7
    int wr = wid >> 1, wc = wid & 1;  // wr: 64-row band (0..3), wc: 64-col band (0..1)
    int bx, by;
    swz_decode(blockIdx.x, nx, M >> 8, bx, by);
    int row0 = by * 256, col0 = bx * 128;

    // staging: wave wid covers A rows [wid*32, +32) (2 glds) and B rows
    // [wid*16, +16) (1 glds). lane -> row = lane>>2, SWIZZLED source group.
    int sgrp = ((lane & 3) ^ ((lane >> 3) & 3)) * 8;   // swizzled source col (elems)
    const short* Ag = (const short*)A + (size_t)(row0 + wid * 32 + (lane >> 2)) * lda + sgrp;
    const short* Wg = (const short*)W + (size_t)(col0 + wid * 16 + (lane >> 2)) * K + sgrp;
    size_t astep16 = (size_t)16 * lda;
    int ldsA = wid * 32 * 32;   // wave-uniform element offsets; HW adds lane*16B
    int ldsB = wid * 16 * 32;

#if HAS_GLDS
#define STAGE(buf, k0)                                                \
    do {                                                              \
        glds16(Ag + (k0), &sm.st.As[buf][ldsA]);                      \
        glds16(Ag + astep16 + (k0), &sm.st.As[buf][ldsA + 16 * 32]);  \
        glds16(Wg + (k0), &sm.st.Bs[buf][ldsB]);                      \
    } while (0)
#else
#define STAGE(buf, k0)                                                               \
    do {                                                                             \
        *(short8v*)(&sm.st.As[buf][ldsA] + lane * 8) = *(const short8v*)(Ag + (k0)); \
        *(short8v*)(&sm.st.As[buf][ldsA + 16 * 32] + lane * 8) = *(const short8v*)(Ag + astep16 + (k0)); \
        *(short8v*)(&sm.st.Bs[buf][ldsB] + lane * 8) = *(const short8v*)(Wg + (k0)); \
    } while (0)
#endif

    f32x4 acc[4][4] = {};
    int frow_a = wr * 64 + (lane & 15);
    int frow_b = wc * 64 + (lane & 15);
    // swizzled fragment k-offset (elements): gk ^ ((row>>1)&3), row mod-4 term
    // depends only on lane&15 (band/f contributions are 0 mod 4 after >>1).
    int fks = (((lane >> 4) ^ (((lane & 15) >> 1) & 3)) * 8);

    int nt = K >> 5;
#if HAS_GLDS
    // counted-vmcnt pipeline, depth 2, 3 slots. 3 glds per STAGE per wave.
    STAGE(0, 0);
    if (nt > 1) STAGE(1, 32);
    int sc = 0;
    for (int t = 0; t < nt; ++t) {
        int sn = sc + 2; if (sn >= 3) sn -= 3;
        if (t + 2 < nt) {
            STAGE(sn, (t + 2) << 5);
            asm volatile("s_waitcnt vmcnt(6)" ::: "memory");
        } else if (t + 1 < nt) {
            asm volatile("s_waitcnt vmcnt(3)" ::: "memory");
        } else {
            asm volatile("s_waitcnt vmcnt(0)" ::: "memory");
        }
        __builtin_amdgcn_s_barrier();          // A: everyone's tile-t loads landed
        __builtin_amdgcn_sched_barrier(0);
        short8v a[4], b[4];
#pragma unroll
        for (int m = 0; m < 4; ++m) a[m] = *(const short8v*)&sm.st.As[sc][(frow_a + m * 16) * 32 + fks];
#pragma unroll
        for (int n = 0; n < 4; ++n) b[n] = *(const short8v*)&sm.st.Bs[sc][(frow_b + n * 16) * 32 + fks];
        __builtin_amdgcn_s_setprio(1);
#pragma unroll
        for (int m = 0; m < 4; ++m)
#pragma unroll
            for (int n = 0; n < 4; ++n)
                acc[m][n] = __builtin_amdgcn_mfma_f32_16x16x32_bf16(a[m], b[n], acc[m][n], 0, 0, 0);
        __builtin_amdgcn_s_setprio(0);
        __builtin_amdgcn_sched_barrier(0);
        __builtin_amdgcn_s_barrier();          // B: all waves consumed tile t
        ++sc; if (sc >= 3) sc = 0;
    }
#else
    STAGE(0, 0);
    __syncthreads();
    int cur = 0;
    for (int t = 0; t < nt; ++t) {
        if (t + 1 < nt) STAGE(cur ^ 1, (t + 1) << 5);
        short8v a[4], b[4];
#pragma unroll
        for (int m = 0; m < 4; ++m) a[m] = *(const short8v*)&sm.st.As[cur][(frow_a + m * 16) * 32 + fks];
#pragma unroll
        for (int n = 0; n < 4; ++n) b[n] = *(const short8v*)&sm.st.Bs[cur][(frow_b + n * 16) * 32 + fks];
#pragma unroll
        for (int m = 0; m < 4; ++m)
#pragma unroll
            for (int n = 0; n < 4; ++n)
                acc[m][n] = __builtin_amdgcn_mfma_f32_16x16x32_bf16(a[m], b[n], acc[m][n], 0, 0, 0);
        if (t + 1 < nt) { __syncthreads(); cur ^= 1; }
    }
#endif
#undef STAGE

    // ---- epilogue: LDS-staged coalesced bf16 stores (ACC: RMW during store) ----
    __syncthreads();   // staging ring dead; overlay output buffer
    int lr = (lane >> 4) * 4;
    int lc = lane & 15;
#pragma unroll
    for (int n = 0; n < 4; ++n) {
        int c = wc * 64 + n * 16 + lc;
        float bv = BIAS ? bias[col0 + c] : 0.0f;
#pragma unroll
        for (int m = 0; m < 4; ++m) {
#pragma unroll
            for (int j = 0; j < 4; ++j) {
                float v = acc[m][n][j] + bv;
                if (GELU) v = gelu_f(v);
                sm.obf[wr * 64 + m * 16 + lr + j][c] = bf16s(v);
            }
        }
    }
    __syncthreads();
    short* yb = (short*)Yb + (size_t)row0 * ldyb + col0;
#pragma unroll
    for (int it = 0; it < 8; ++it) {
        int r = (tid >> 4) + it * 32;
        int c8 = (tid & 15) * 8;
        short8v v = *(const short8v*)&sm.obf[r][c8];
        short* yp = yb + (size_t)r * ldyb + c8;
        if (ACC) {
            short8v o = *(const short8v*)yp;
#pragma unroll
            for (int e = 0; e < 8; ++e) v[e] = bf16s(bf2f(v[e]) + bf2f(o[e]));
        }
        *(short8v*)yp = v;
    }
}

// ---------------- MFMA attention, barrier-free, XCD-swizzled ----------------
__global__ __launch_bounds__(256) void attn_mfma_kernel(
    const __hip_bfloat16* __restrict__ qkv,
    const float* __restrict__ biasT,
    __hip_bfloat16* __restrict__ o,
    int T, float scale, int nwin) {
    __shared__ __align__(16) short Vt[4][32][72];   // [wave][d][kt]  (V transposed)
    __shared__ __align__(16) short Pl[4][64][40];   // [wave][r][half-K cols]
    const int tid = threadIdx.x, lane = tid & 63, wv = tid >> 6;
    int p, hg;
    {
        int L = blockIdx.x;
        if (nwin & 7) { hg = L % 3; p = L / 3; }
        else { int r = L & 7, pos = L >> 3; hg = pos % 3; p = (pos / 3) * 8 + r; }
    }
    const int h = hg * 4 + wv;
    const short* q_base = (const short*)qkv + (size_t)p * T * N3;

    const int fr = lane & 15;
    const int fk = (lane >> 4) * 8;
    const int lg = lane >> 4;
    const int lc = lane & 15;

    short8v aq[4], bk[4];
#pragma unroll
    for (int m = 0; m < 4; ++m) {
        const short* qp = q_base + (size_t)(m * 16 + fr) * N3 + h * 32 + fk;
        aq[m] = *(const short8v*)qp;
        bk[m] = *(const short8v*)(qp + 384);
    }

    for (int ch = lane; ch < T * 4; ch += 64) {
        int t = ch >> 2, cq = ch & 3;
        short8v v8 = *(const short8v*)(q_base + (size_t)t * N3 + 768 + h * 32 + cq * 8);
#pragma unroll
        for (int e = 0; e < 8; ++e) Vt[wv][cq * 8 + e][t] = v8[e];
    }
    for (int idx = lane; idx < (64 - T) * 32; idx += 64) {
        int t = T + (idx >> 5), d = idx & 31;
        Vt[wv][d][t] = 0;
    }

    f32x4 acc[4][4] = {};
#pragma unroll
    for (int m = 0; m < 4; ++m)
#pragma unroll
        for (int n = 0; n < 4; ++n)
            acc[m][n] = __builtin_amdgcn_mfma_f32_16x16x32_bf16(aq[m], bk[n], acc[m][n], 0, 0, 0);

    const float* bh = biasT ? (biasT + (size_t)h * 4096) : nullptr;
    float p2[4][4], p3[4][4];
#pragma unroll
    for (int m = 0; m < 4; ++m) {
#pragma unroll
        for (int j = 0; j < 4; ++j) {
            int r = m * 16 + lg * 4 + j;
            float v[4];
            if (bh) {
                float4 bv4 = *(const float4*)(bh + r * 64 + lc * 4);
#pragma unroll
                for (int n = 0; n < 4; ++n) v[n] = acc[m][n][j] * scale + ((const float*)&bv4)[n];
            } else {
#pragma unroll
                for (int n = 0; n < 4; ++n) v[n] = acc[m][n][j] * scale;
            }
#pragma unroll
            for (int n = 0; n < 4; ++n)
                if (n * 16 + lc >= T) v[n] = -1e30f;
            float mx = fmaxf(fmaxf(v[0], v[1]), fmaxf(v[2], v[3]));
#pragma unroll
            for (int off = 1; off < 16; off <<= 1) mx = fmaxf(mx, __shfl_xor(mx, off));
            float s = 0.f;
#pragma unroll
            for (int n = 0; n < 4; ++n) { v[n] = __expf(v[n] - mx); s += v[n]; }
#pragma unroll
            for (int off = 1; off < 16; off <<= 1) s += __shfl_xor(s, off);
            float inv = 1.0f / s;
            Pl[wv][r][lc]      = bf16s(v[0] * inv);
            Pl[wv][r][16 + lc] = bf16s(v[1] * inv);
            p2[m][j] = v[2] * inv;
            p3[m][j] = v[3] * inv;
        }
    }

    f32x4 oacc[4][2] = {};
    {
        short8v ap[4], bv[2];
#pragma unroll
        for (int m = 0; m < 4; ++m) ap[m] = *(const short8v*)&Pl[wv][m * 16 + fr][fk];
#pragma unroll
        for (int n = 0; n < 2; ++n) bv[n] = *(const short8v*)&Vt[wv][n * 16 + fr][fk];
#pragma unroll
        for (int m = 0; m < 4; ++m)
#pragma unroll
            for (int n = 0; n < 2; ++n)
                oacc[m][n] = __builtin_amdgcn_mfma_f32_16x16x32_bf16(ap[m], bv[n], oacc[m][n], 0, 0, 0);
    }
#pragma unroll
    for (int m = 0; m < 4; ++m)
#pragma unroll
        for (int j = 0; j < 4; ++j) {
            int r = m * 16 + lg * 4 + j;
            Pl[wv][r][lc]      = bf16s(p2[m][j]);
            Pl[wv][r][16 + lc] = bf16s(p3[m][j]);
        }
    {
        short8v ap[4], bv[2];
#pragma unroll
        for (int m = 0; m < 4; ++m) ap[m] = *(const short8v*)&Pl[wv][m * 16 + fr][fk];
#pragma unroll
        for (int n = 0; n < 2; ++n) bv[n] = *(const short8v*)&Vt[wv][n * 16 + fr][32 + fk];
#pragma unroll
        for (int m = 0; m < 4; ++m)
#pragma unroll
            for (int n = 0; n < 2; ++n)
                oacc[m][n] = __builtin_amdgcn_mfma_f32_16x16x32_bf16(ap[m], bv[n], oacc[m][n], 0, 0, 0);
    }

    short* ob = (short*)o;
#pragma unroll
    for (int m = 0; m < 4; ++m)
#pragma unroll
        for (int j = 0; j < 4; ++j) {
            int r = m * 16 + lg * 4 + j;
            if (r < T) {
#pragma unroll
                for (int n = 0; n < 2; ++n)
                    ob[((size_t)p * T + r) * CC + h * 32 + n * 16 + lc] = bf16s(oacc[m][n][j]);
            }
        }
}

// ---------------- host ----------------
extern "C" void kernel_launch(void* const* d_in, const int* in_sizes, int n_in,
                              void* d_out, int out_size, void* d_ws, size_t ws_size,
                              hipStream_t stream) {
    const float* cls_in   = (const float*)d_in[0];
    const float* patch_in = (const float*)d_in[1];
    const float* qkv_w    = (const float*)d_in[2];
    const float* qkv_b    = (const float*)d_in[3];
    const float* proj_w   = (const float*)d_in[4];
    const float* proj_b   = (const float*)d_in[5];
    const float* rel_pos  = (const float*)d_in[6];
    const float* ln0w = (const float*)d_in[7];
    const float* ln0b = (const float*)d_in[8];
    const float* ln1w = (const float*)d_in[9];
    const float* ln1b = (const float*)d_in[10];
    const float* ln2w = (const float*)d_in[11];
    const float* ln2b = (const float*)d_in[12];
    const float* w1 = (const float*)d_in[13];
    const float* b1 = (const float*)d_in[14];
    const float* w2 = (const float*)d_in[15];
    const float* b2 = (const float*)d_in[16];

    float* WS = (float*)d_ws;
    size_t avail = ws_size / 4;

    // bf16 residual stream: 2048*50*384 bf16 = 19,660,800 f32 slots
    const size_t OUT_FB = 19660800;
    const size_t WB_F   = 1769472;           // bf16 weights (f32 slots)
    const size_t BT_F   = 49152;             // bias table 12*64*64 fp32
    __hip_bfloat16* OUTB = (__hip_bfloat16*)WS;
    __hip_bfloat16* WB = (__hip_bfloat16*)(WS + OUT_FB);
    __hip_bfloat16* qwb = WB;                                   // 2*1152*384
    __hip_bfloat16* pwb = WB + 884736;                          // 2*384*384
    __hip_bfloat16* w1b = WB + 1179648;                         // 2*1536*384
    __hip_bfloat16* w2b = WB + 2359296;                         // 2*384*1536
    float* biasTbuf = WS + OUT_FB + WB_F;

    // cw = 1024. cw*NTT must be a multiple of 256 (cw >= 128).
    int cw = 1024;
    while (cw > 128 && OUT_FB + WB_F + BT_F + (size_t)cw * 48000 > avail) cw >>= 1;
    float* fbase = WS + OUT_FB + WB_F + BT_F;
    __hip_bfloat16* Xb = (__hip_bfloat16*)fbase;
    __hip_bfloat16* Qb = (__hip_bfloat16*)(fbase + (size_t)cw * 9600);
    __hip_bfloat16* Hb = Qb;   // MLP hidden reuses Qb region
    const float scale = 0.17677669529663687f;

    f2bf_kernel<<<dim3((884736 / 4 + 255) / 256), dim3(256), 0, stream>>>(qkv_w, qwb, 884736);
    f2bf_kernel<<<dim3((294912 / 4 + 255) / 256), dim3(256), 0, stream>>>(proj_w, pwb, 294912);
    f2bf_kernel<<<dim3((1179648 / 4 + 255) / 256), dim3(256), 0, stream>>>(w1, w1b, 1179648);
    f2bf_kernel<<<dim3((1179648 / 4 + 255) / 256), dim3(256), 0, stream>>>(w2, w2b, 1179648);

    pack_cls_kernel<<<dim3(BB * 6), dim3(256), 0, stream>>>(cls_in, OUTB);
    pack_patch_kernel<<<dim3(BB * 56 * 6), dim3(256), 0, stream>>>(patch_in, OUTB);

    for (int i = 0; i < NBB; ++i) {
        const __hip_bfloat16* qw = qwb + (size_t)i * N3 * CC;
        const float* qb = qkv_b + (size_t)i * N3;
        const __hip_bfloat16* pw = pwb + (size_t)i * CC * CC;
        const float* pb = proj_b + (size_t)i * CC;
        const float* rp = rel_pos + (size_t)i * NHH * 169;
        const __hip_bfloat16* w1i = w1b + (size_t)i * HIDD * CC;
        const float* b1i = b1 + (size_t)i * HIDD;
        const __hip_bfloat16* w2i = w2b + (size_t)i * CC * HIDD;
        const float* b2i = b2 + (size_t)i * CC;

        bias_precompute_kernel<<<dim3(NHH), dim3(256), 0, stream>>>(rp, biasTbuf);

        // ---- stage A: cls attention across 64 windows of each image (T=64) ----
        ln_kernel<<<dim3(2048 / 4), dim3(256), 0, stream>>>(OUTB, LDOUT, ln0w + i * CC, ln0b + i * CC, Xb, CC, 2048);
        gemm_bf16_kernel<1, 0, 0><<<dim3((N3 / 128) * (2048 / 256)), dim3(512), 0, stream>>>(
            Xb, CC, qw, qb, Qb, N3, 2048, N3, CC, N3 / 128);
        attn_mfma_kernel<<<dim3(BB * 3), dim3(256), 0, stream>>>(Qb, nullptr, Xb, 64, scale, BB);
        gemm_bf16_kernel<1, 0, 1><<<dim3((CC / 128) * (2048 / 256)), dim3(512), 0, stream>>>(
            Xb, CC, pw, pb, OUTB, LDOUT, 2048, CC, CC, CC / 128);

        // ---- stage B: windowed attention with rel-pos bias (T=50) ----
        for (int w0 = 0; w0 < NWW; w0 += cw) {
            __hip_bfloat16* outc = OUTB + (size_t)w0 * LDOUT;
            int Mr = cw * NTT;
            ln_kernel<<<dim3(Mr / 4), dim3(256), 0, stream>>>(outc, CC, ln1w + i * CC, ln1b + i * CC, Xb, CC, Mr);
            gemm_bf16_kernel<1, 0, 0><<<dim3((N3 / 128) * (Mr / 256)), dim3(512), 0, stream>>>(
                Xb, CC, qw, qb, Qb, N3, Mr, N3, CC, N3 / 128);
            attn_mfma_kernel<<<dim3(cw * 3), dim3(256), 0, stream>>>(Qb, biasTbuf, Xb, NTT, scale, cw);
            gemm_bf16_kernel<1, 0, 1><<<dim3((CC / 128) * (Mr / 256)), dim3(512), 0, stream>>>(
                Xb, CC, pw, pb, outc, CC, Mr, CC, CC, CC / 128);
        }

        // ---- stage C: MLP ----
        for (int w0 = 0; w0 < NWW; w0 += cw) {
            __hip_bfloat16* outc = OUTB + (size_t)w0 * LDOUT;
            int Mr = cw * NTT;
            ln_kernel<<<dim3(Mr / 4), dim3(256), 0, stream>>>(outc, CC, ln2w + i * CC, ln2b + i * CC, Xb, CC, Mr);
            gemm_bf16_kernel<1, 1, 0><<<dim3((HIDD / 128) * (Mr / 256)), dim3(512), 0, stream>>>(
                Xb, CC, w1i, b1i, Hb, HIDD, Mr, HIDD, CC, HIDD / 128);
            gemm_bf16_kernel<1, 0, 1><<<dim3((CC / 128) * (Mr / 256)), dim3(512), 0, stream>>>(
                Hb, HIDD, w2i, b2i, outc, CC, Mr, CC, HIDD, CC / 128);
        }
    }

    unpack_cls_kernel<<<dim3(BB * 6), dim3(256), 0, stream>>>(OUTB, (float*)d_out);
    unpack_patch_kernel<<<dim3(BB * 56 * 6), dim3(256), 0, stream>>>(OUTB, (float*)d_out + 786432);
}

// Round 15
// 1778.301 us; speedup vs baseline: 1.1521x; 1.0514x over previous
//
#include <hip/hip_runtime.h>
#include <hip/hip_bf16.h>
#include <cstdint>
#include <cstddef>

// ---- problem constants ----
#define BB    32
#define CC    384
#define NHH   12
#define HDD   32
#define WSS   7
#define HKK   8
#define NBB   2
#define HIDD  1536
#define NTT   50          // tokens per window (1 cls + 49 patch)
#define NWW   2048        // B*HK*HK windows
#define LDOUT 19200       // 50*384
#define N3    1152        // 3*C

typedef __attribute__((ext_vector_type(8))) short short8v;
typedef __attribute__((ext_vector_type(4))) float f32x4;

#if defined(__has_builtin)
#if __has_builtin(__builtin_amdgcn_global_load_lds)
#define HAS_GLDS 1
#endif
#endif
#ifndef HAS_GLDS
#define HAS_GLDS 0
#endif

// sigmoid-form GELU: x*sigmoid(1.702x). ~5 VALU ops, 1 transcendental.
// |err| vs exact-erf <= 0.02 only for |h|>1 (~1% of elements, h~N(0,0.39^2));
// after w2 (sigma 0.02, random signs) Delta-out ~ 0.004 << 0.0625 margin.
static __device__ __forceinline__ float gelu_f(float x) {
    return x / (1.0f + __expf(-1.702f * x));
}

static __device__ __forceinline__ short bf16s(float x) {
    __hip_bfloat16 b = __float2bfloat16(x);
    return *(short*)&b;
}

static __device__ __forceinline__ float bf2f(short s) {
    union { unsigned int u; float f; } cv;
    cv.u = ((unsigned int)(unsigned short)s) << 16;
    return cv.f;
}

#if HAS_GLDS
static __device__ __forceinline__ void glds16(const short* g, short* l) {
    __builtin_amdgcn_global_load_lds(
        (const __attribute__((address_space(1))) unsigned int*)g,
        (__attribute__((address_space(3))) unsigned int*)l,
        16, 0, 0);
}
#endif

// XCD-aware decode: keep all nx column-blocks of one row-panel on ONE XCD.
static __device__ __forceinline__ void swz_decode(int L, int nx, int ny, int& bx, int& by) {
    if (ny & 7) {
        bx = L % nx; by = L / nx;
    } else {
        int r = L & 7, pos = L >> 3;
        bx = pos % nx;
        by = (pos / nx) * 8 + r;
    }
}

// ---------------- pack / unpack (fp32 <-> bf16 residual stream) ----------------
__global__ void pack_cls_kernel(const float* __restrict__ cls, __hip_bfloat16* __restrict__ out) {
    __shared__ float lds[64][65];
    int bid = blockIdx.x;
    int b = bid / 6, cc = bid % 6, c0 = cc * 64;
    int tid = threadIdx.x;
    for (int idx = tid; idx < 64 * 64; idx += 256) {
        int k = idx & 63, cl = idx >> 6;
        lds[cl][k] = cls[((size_t)b * CC + c0 + cl) * 64 + k];
    }
    __syncthreads();
    short* ob = (short*)out;
    for (int idx = tid; idx < 64 * 64; idx += 256) {
        int cl = idx & 63, k = idx >> 6;
        ob[(size_t)(b * 64 + k) * LDOUT + c0 + cl] = bf16s(lds[cl][k]);
    }
}

__global__ void pack_patch_kernel(const float* __restrict__ patch, __hip_bfloat16* __restrict__ out) {
    __shared__ float lds[64][57];
    int bid = blockIdx.x;
    int b = bid / 336, rem = bid % 336;
    int y = rem / 6, cc = rem % 6, c0 = cc * 64;
    int tid = threadIdx.x;
    for (int idx = tid; idx < 64 * 56; idx += 256) {
        int cl = idx / 56, x = idx % 56;
        lds[cl][x] = patch[(((size_t)b * CC + c0 + cl) * 56 + y) * 56 + x];
    }
    __syncthreads();
    int wsy = y % 7, hky = y / 7;
    short* ob = (short*)out;
    for (int idx = tid; idx < 64 * 56; idx += 256) {
        int cl = idx & 63, x = idx >> 6;
        int tok = 1 + wsy * 7 + (x % 7);
        int win = b * 64 + hky * 8 + (x / 7);
        ob[((size_t)win * NTT + tok) * CC + c0 + cl] = bf16s(lds[cl][x]);
    }
}

__global__ void unpack_cls_kernel(const __hip_bfloat16* __restrict__ out, float* __restrict__ cls_out) {
    __shared__ float lds[64][65];
    int bid = blockIdx.x;
    int b = bid / 6, cc = bid % 6, c0 = cc * 64;
    int tid = threadIdx.x;
    const short* ob = (const short*)out;
    for (int idx = tid; idx < 64 * 64; idx += 256) {
        int cl = idx & 63, k = idx >> 6;
        lds[cl][k] = bf2f(ob[(size_t)(b * 64 + k) * LDOUT + c0 + cl]);
    }
    __syncthreads();
    for (int idx = tid; idx < 64 * 64; idx += 256) {
        int k = idx & 63, cl = idx >> 6;
        cls_out[((size_t)b * CC + c0 + cl) * 64 + k] = lds[cl][k];
    }
}

__global__ void unpack_patch_kernel(const __hip_bfloat16* __restrict__ out, float* __restrict__ patch_out) {
    __shared__ float lds[64][57];
    int bid = blockIdx.x;
    int b = bid / 336, rem = bid % 336;
    int y = rem / 6, cc = rem % 6, c0 = cc * 64;
    int tid = threadIdx.x;
    int wsy = y % 7, hky = y / 7;
    const short* ob = (const short*)out;
    for (int idx = tid; idx < 64 * 56; idx += 256) {
        int cl = idx & 63, x = idx >> 6;
        int tok = 1 + wsy * 7 + (x % 7);
        int win = b * 64 + hky * 8 + (x / 7);
        lds[cl][x] = bf2f(ob[((size_t)win * NTT + tok) * CC + c0 + cl]);
    }
    __syncthreads();
    for (int idx = tid; idx < 64 * 56; idx += 256) {
        int cl = idx / 56, x = idx % 56;
        patch_out[((size_t)b * CC + c0 + cl) * 3136 + y * 56 + x] = lds[cl][x];
    }
}

// ---------------- fp32 -> bf16 weight conversion ----------------
__global__ void f2bf_kernel(const float* __restrict__ in, __hip_bfloat16* __restrict__ out, int n) {
    int i = (blockIdx.x * 256 + threadIdx.x) * 4;
    if (i + 3 < n) {
        float4 v = *(const float4*)(in + i);
        out[i + 0] = __float2bfloat16(v.x);
        out[i + 1] = __float2bfloat16(v.y);
        out[i + 2] = __float2bfloat16(v.z);
        out[i + 3] = __float2bfloat16(v.w);
    } else {
        for (; i < n; ++i) out[i] = __float2bfloat16(in[i]);
    }
}

// ---------------- rel-pos bias table, fragment-ordered: [12][64 r][16 lc][4 n] fp32 ----------------
__global__ void bias_precompute_kernel(const float* __restrict__ rp, float* __restrict__ biasT) {
    int h = blockIdx.x;
    for (int idx = threadIdx.x; idx < 4096; idx += 256) {
        int qt = idx >> 6, kt = idx & 63;
        float v = 0.f;
        if (qt >= 1 && qt < NTT && kt >= 1 && kt < NTT) {
            int qp = qt - 1, kp = kt - 1;
            int qy = qp / 7, qx = qp - qy * 7;
            int ky = kp / 7, kx = kp - ky * 7;
            int ridx = ((ky - qy + 16) % 13) * 13 + ((kx - qx + 16) % 13);
            v = rp[h * 169 + ridx];
        }
        biasT[h * 4096 + qt * 64 + (kt & 15) * 4 + (kt >> 4)] = v;
    }
}

// ---------------- LayerNorm (bf16 in) -> bf16 out ----------------
__global__ void ln_kernel(const __hip_bfloat16* __restrict__ x, int ldx,
                          const float* __restrict__ w, const float* __restrict__ b,
                          __hip_bfloat16* __restrict__ y, int ldy, int M) {
    int wave = threadIdx.x >> 6, lane = threadIdx.x & 63;
    int row = blockIdx.x * 4 + wave;
    if (row >= M) return;
    const ushort2* xr = (const ushort2*)((const short*)x + (size_t)row * ldx);
    float2 vals[3];
    float s = 0.f;
#pragma unroll
    for (int j = 0; j < 3; ++j) {
        ushort2 u = xr[lane + j * 64];
        vals[j].x = bf2f((short)u.x);
        vals[j].y = bf2f((short)u.y);
        s += vals[j].x + vals[j].y;
    }
#pragma unroll
    for (int off = 32; off > 0; off >>= 1) s += __shfl_xor(s, off);
    float mean = s * (1.0f / 384.0f);
    float vs = 0.f;
#pragma unroll
    for (int j = 0; j < 3; ++j) {
        float dx = vals[j].x - mean, dy = vals[j].y - mean;
        vs += dx * dx + dy * dy;
    }
#pragma unroll
    for (int off = 32; off > 0; off >>= 1) vs += __shfl_xor(vs, off);
    float inv = rsqrtf(vs * (1.0f / 384.0f) + 1e-6f);
    const float2* w2 = (const float2*)w;
    const float2* b2 = (const float2*)b;
    ushort* yr = (ushort*)y + (size_t)row * ldy;
#pragma unroll
    for (int j = 0; j < 3; ++j) {
        int c = lane + j * 64;
        float2 wv = w2[c], bv = b2[c];
        ushort2 o;
        o.x = (ushort)bf16s((vals[j].x - mean) * inv * wv.x + bv.x);
        o.y = (ushort)bf16s((vals[j].y - mean) * inv * wv.y + bv.y);
        *(ushort2*)(yr + c * 2) = o;
    }
}

// ---------------- bf16 MFMA GEMM v7: Y = A[M,K] @ W[N,K]^T ----------------
// R14 structure (best measured): 256x128 tile, 8 waves (4M x 2N), BK=32,
// 3-slot ring (72 KB -> 2 blocks/CU), counted-vmcnt depth-2 (6/3/0),
// both-sides XOR bank swizzle (R14-verified: conflicts 8.6M -> 1.2M).
// NEW: K is a template constant and the K-loop is FULLY UNROLLED ->
// staging addresses fold to immediate offsets (<=3KB, fits 13-bit global
// offset), slot rotation + vmcnt ladder constant-fold, zero loop VALU.
// launch_bounds(512,4) (R10 lesson: never under-budget the accumulator).
template <int BIAS, int GELU, int ACC, int KT>
__global__ __launch_bounds__(512, 4) void gemm_bf16_kernel(
    const __hip_bfloat16* __restrict__ A, int lda,
    const __hip_bfloat16* __restrict__ W,
    const float* __restrict__ bias,
    __hip_bfloat16* __restrict__ Yb, int ldyb,
    int M, int N, int nx) {
    __shared__ __align__(16) union SMemU {
        struct { short As[3][256 * 32]; short Bs[3][128 * 32]; } st;  // 72 KB ring
        short obf[256][132];   // 67.6 KB bf16 output tile
    } sm;
    int tid = threadIdx.x;
    int lane = tid & 63;
    int wid = tid >> 6;               // 0..7
    int wr = wid >> 1, wc = wid & 1;  // wr: 64-row band (0..3), wc: 64-col band (0..1)
    int bx, by;
    swz_decode(blockIdx.x, nx, M >> 8, bx, by);
    int row0 = by * 256, col0 = bx * 128;

    // staging: wave wid covers A rows [wid*32, +32) (2 glds) and B rows
    // [wid*16, +16) (1 glds). lane -> row = lane>>2, SWIZZLED source group.
    int sgrp = ((lane & 3) ^ ((lane >> 3) & 3)) * 8;   // swizzled source col (elems)
    const short* Ag = (const short*)A + (size_t)(row0 + wid * 32 + (lane >> 2)) * lda + sgrp;
    const short* Wg = (const short*)W + (size_t)(col0 + wid * 16 + (lane >> 2)) * KT + sgrp;
    size_t astep16 = (size_t)16 * lda;
    int ldsA = wid * 32 * 32;   // wave-uniform element offsets; HW adds lane*16B
    int ldsB = wid * 16 * 32;

#if HAS_GLDS
#define STAGE(buf, k0)                                                \
    do {                                                              \
        glds16(Ag + (k0), &sm.st.As[buf][ldsA]);                      \
        glds16(Ag + astep16 + (k0), &sm.st.As[buf][ldsA + 16 * 32]);  \
        glds16(Wg + (k0), &sm.st.Bs[buf][ldsB]);                      \
    } while (0)
#else
#define STAGE(buf, k0)                                                               \
    do {                                                                             \
        *(short8v*)(&sm.st.As[buf][ldsA] + lane * 8) = *(const short8v*)(Ag + (k0)); \
        *(short8v*)(&sm.st.As[buf][ldsA + 16 * 32] + lane * 8) = *(const short8v*)(Ag + astep16 + (k0)); \
        *(short8v*)(&sm.st.Bs[buf][ldsB] + lane * 8) = *(const short8v*)(Wg + (k0)); \
    } while (0)
#endif

    f32x4 acc[4][4] = {};
    int frow_a = wr * 64 + (lane & 15);
    int frow_b = wc * 64 + (lane & 15);
    // swizzled fragment k-offset (elements): gk ^ ((row>>1)&3), row mod-4 term
    // depends only on lane&15 (band/f contributions are 0 mod 4 after >>1).
    int fks = (((lane >> 4) ^ (((lane & 15) >> 1) & 3)) * 8);

    constexpr int nt = KT >> 5;
#if HAS_GLDS
    // counted-vmcnt pipeline, depth 2, 3 slots; fully unrolled (KT constexpr).
    STAGE(0, 0);
    if (nt > 1) STAGE(1, 32);
#pragma unroll
    for (int t = 0; t < nt; ++t) {
        const int sc = t % 3;
        const int sn = (t + 2) % 3;
        if (t + 2 < nt) {
            STAGE(sn, (t + 2) << 5);
            asm volatile("s_waitcnt vmcnt(6)" ::: "memory");
        } else if (t + 1 < nt) {
            asm volatile("s_waitcnt vmcnt(3)" ::: "memory");
        } else {
            asm volatile("s_waitcnt vmcnt(0)" ::: "memory");
        }
        __builtin_amdgcn_s_barrier();          // A: everyone's tile-t loads landed
        __builtin_amdgcn_sched_barrier(0);
        short8v a[4], b[4];
#pragma unroll
        for (int m = 0; m < 4; ++m) a[m] = *(const short8v*)&sm.st.As[sc][(frow_a + m * 16) * 32 + fks];
#pragma unroll
        for (int n = 0; n < 4; ++n) b[n] = *(const short8v*)&sm.st.Bs[sc][(frow_b + n * 16) * 32 + fks];
        __builtin_amdgcn_s_setprio(1);
#pragma unroll
        for (int m = 0; m < 4; ++m)
#pragma unroll
            for (int n = 0; n < 4; ++n)
                acc[m][n] = __builtin_amdgcn_mfma_f32_16x16x32_bf16(a[m], b[n], acc[m][n], 0, 0, 0);
        __builtin_amdgcn_s_setprio(0);
        __builtin_amdgcn_sched_barrier(0);
        __builtin_amdgcn_s_barrier();          // B: all waves consumed tile t
    }
#else
    STAGE(0, 0);
    __syncthreads();
#pragma unroll
    for (int t = 0; t < nt; ++t) {
        const int cur = t & 1;
        if (t + 1 < nt) STAGE(cur ^ 1, (t + 1) << 5);
        short8v a[4], b[4];
#pragma unroll
        for (int m = 0; m < 4; ++m) a[m] = *(const short8v*)&sm.st.As[cur][(frow_a + m * 16) * 32 + fks];
#pragma unroll
        for (int n = 0; n < 4; ++n) b[n] = *(const short8v*)&sm.st.Bs[cur][(frow_b + n * 16) * 32 + fks];
#pragma unroll
        for (int m = 0; m < 4; ++m)
#pragma unroll
            for (int n = 0; n < 4; ++n)
                acc[m][n] = __builtin_amdgcn_mfma_f32_16x16x32_bf16(a[m], b[n], acc[m][n], 0, 0, 0);
        if (t + 1 < nt) __syncthreads();
    }
#endif
#undef STAGE

    // ---- epilogue: LDS-staged coalesced bf16 stores (ACC: RMW during store) ----
    __syncthreads();   // staging ring dead; overlay output buffer
    int lr = (lane >> 4) * 4;
    int lc = lane & 15;
#pragma unroll
    for (int n = 0; n < 4; ++n) {
        int c = wc * 64 + n * 16 + lc;
        float bv = BIAS ? bias[col0 + c] : 0.0f;
#pragma unroll
        for (int m = 0; m < 4; ++m) {
#pragma unroll
            for (int j = 0; j < 4; ++j) {
                float v = acc[m][n][j] + bv;
                if (GELU) v = gelu_f(v);
                sm.obf[wr * 64 + m * 16 + lr + j][c] = bf16s(v);
            }
        }
    }
    __syncthreads();
    short* yb = (short*)Yb + (size_t)row0 * ldyb + col0;
#pragma unroll
    for (int it = 0; it < 8; ++it) {
        int r = (tid >> 4) + it * 32;
        int c8 = (tid & 15) * 8;
        short8v v = *(const short8v*)&sm.obf[r][c8];
        short* yp = yb + (size_t)r * ldyb + c8;
        if (ACC) {
            short8v o = *(const short8v*)yp;
#pragma unroll
            for (int e = 0; e < 8; ++e) v[e] = bf16s(bf2f(v[e]) + bf2f(o[e]));
        }
        *(short8v*)yp = v;
    }
}

// ---------------- MFMA attention, barrier-free, XCD-swizzled ----------------
__global__ __launch_bounds__(256) void attn_mfma_kernel(
    const __hip_bfloat16* __restrict__ qkv,
    const float* __restrict__ biasT,
    __hip_bfloat16* __restrict__ o,
    int T, float scale, int nwin) {
    __shared__ __align__(16) short Vt[4][32][72];   // [wave][d][kt]  (V transposed)
    __shared__ __align__(16) short Pl[4][64][40];   // [wave][r][half-K cols]
    const int tid = threadIdx.x, lane = tid & 63, wv = tid >> 6;
    int p, hg;
    {
        int L = blockIdx.x;
        if (nwin & 7) { hg = L % 3; p = L / 3; }
        else { int r = L & 7, pos = L >> 3; hg = pos % 3; p = (pos / 3) * 8 + r; }
    }
    const int h = hg * 4 + wv;
    const short* q_base = (const short*)qkv + (size_t)p * T * N3;

    const int fr = lane & 15;
    const int fk = (lane >> 4) * 8;
    const int lg = lane >> 4;
    const int lc = lane & 15;

    short8v aq[4], bk[4];
#pragma unroll
    for (int m = 0; m < 4; ++m) {
        const short* qp = q_base + (size_t)(m * 16 + fr) * N3 + h * 32 + fk;
        aq[m] = *(const short8v*)qp;
        bk[m] = *(const short8v*)(qp + 384);
    }

    for (int ch = lane; ch < T * 4; ch += 64) {
        int t = ch >> 2, cq = ch & 3;
        short8v v8 = *(const short8v*)(q_base + (size_t)t * N3 + 768 + h * 32 + cq * 8);
#pragma unroll
        for (int e = 0; e < 8; ++e) Vt[wv][cq * 8 + e][t] = v8[e];
    }
    for (int idx = lane; idx < (64 - T) * 32; idx += 64) {
        int t = T + (idx >> 5), d = idx & 31;
        Vt[wv][d][t] = 0;
    }

    f32x4 acc[4][4] = {};
#pragma unroll
    for (int m = 0; m < 4; ++m)
#pragma unroll
        for (int n = 0; n < 4; ++n)
            acc[m][n] = __builtin_amdgcn_mfma_f32_16x16x32_bf16(aq[m], bk[n], acc[m][n], 0, 0, 0);

    const float* bh = biasT ? (biasT + (size_t)h * 4096) : nullptr;
    float p2[4][4], p3[4][4];
#pragma unroll
    for (int m = 0; m < 4; ++m) {
#pragma unroll
        for (int j = 0; j < 4; ++j) {
            int r = m * 16 + lg * 4 + j;
            float v[4];
            if (bh) {
                float4 bv4 = *(const float4*)(bh + r * 64 + lc * 4);
#pragma unroll
                for (int n = 0; n < 4; ++n) v[n] = acc[m][n][j] * scale + ((const float*)&bv4)[n];
            } else {
#pragma unroll
                for (int n = 0; n < 4; ++n) v[n] = acc[m][n][j] * scale;
            }
#pragma unroll
            for (int n = 0; n < 4; ++n)
                if (n * 16 + lc >= T) v[n] = -1e30f;
            float mx = fmaxf(fmaxf(v[0], v[1]), fmaxf(v[2], v[3]));
#pragma unroll
            for (int off = 1; off < 16; off <<= 1) mx = fmaxf(mx, __shfl_xor(mx, off));
            float s = 0.f;
#pragma unroll
            for (int n = 0; n < 4; ++n) { v[n] = __expf(v[n] - mx); s += v[n]; }
#pragma unroll
            for (int off = 1; off < 16; off <<= 1) s += __shfl_xor(s, off);
            float inv = 1.0f / s;
            Pl[wv][r][lc]      = bf16s(v[0] * inv);
            Pl[wv][r][16 + lc] = bf16s(v[1] * inv);
            p2[m][j] = v[2] * inv;
            p3[m][j] = v[3] * inv;
        }
    }

    f32x4 oacc[4][2] = {};
    {
        short8v ap[4], bv[2];
#pragma unroll
        for (int m = 0; m < 4; ++m) ap[m] = *(const short8v*)&Pl[wv][m * 16 + fr][fk];
#pragma unroll
        for (int n = 0; n < 2; ++n) bv[n] = *(const short8v*)&Vt[wv][n * 16 + fr][fk];
#pragma unroll
        for (int m = 0; m < 4; ++m)
#pragma unroll
            for (int n = 0; n < 2; ++n)
                oacc[m][n] = __builtin_amdgcn_mfma_f32_16x16x32_bf16(ap[m], bv[n], oacc[m][n], 0, 0, 0);
    }
#pragma unroll
    for (int m = 0; m < 4; ++m)
#pragma unroll
        for (int j = 0; j < 4; ++j) {
            int r = m * 16 + lg * 4 + j;
            Pl[wv][r][lc]      = bf16s(p2[m][j]);
            Pl[wv][r][16 + lc] = bf16s(p3[m][j]);
        }
    {
        short8v ap[4], bv[2];
#pragma unroll
        for (int m = 0; m < 4; ++m) ap[m] = *(const short8v*)&Pl[wv][m * 16 + fr][fk];
#pragma unroll
        for (int n = 0; n < 2; ++n) bv[n] = *(const short8v*)&Vt[wv][n * 16 + fr][32 + fk];
#pragma unroll
        for (int m = 0; m < 4; ++m)
#pragma unroll
            for (int n = 0; n < 2; ++n)
                oacc[m][n] = __builtin_amdgcn_mfma_f32_16x16x32_bf16(ap[m], bv[n], oacc[m][n], 0, 0, 0);
    }

    short* ob = (short*)o;
#pragma unroll
    for (int m = 0; m < 4; ++m)
#pragma unroll
        for (int j = 0; j < 4; ++j) {
            int r = m * 16 + lg * 4 + j;
            if (r < T) {
#pragma unroll
                for (int n = 0; n < 2; ++n)
                    ob[((size_t)p * T + r) * CC + h * 32 + n * 16 + lc] = bf16s(oacc[m][n][j]);
            }
        }
}

// ---------------- host ----------------
extern "C" void kernel_launch(void* const* d_in, const int* in_sizes, int n_in,
                              void* d_out, int out_size, void* d_ws, size_t ws_size,
                              hipStream_t stream) {
    const float* cls_in   = (const float*)d_in[0];
    const float* patch_in = (const float*)d_in[1];
    const float* qkv_w    = (const float*)d_in[2];
    const float* qkv_b    = (const float*)d_in[3];
    const float* proj_w   = (const float*)d_in[4];
    const float* proj_b   = (const float*)d_in[5];
    const float* rel_pos  = (const float*)d_in[6];
    const float* ln0w = (const float*)d_in[7];
    const float* ln0b = (const float*)d_in[8];
    const float* ln1w = (const float*)d_in[9];
    const float* ln1b = (const float*)d_in[10];
    const float* ln2w = (const float*)d_in[11];
    const float* ln2b = (const float*)d_in[12];
    const float* w1 = (const float*)d_in[13];
    const float* b1 = (const float*)d_in[14];
    const float* w2 = (const float*)d_in[15];
    const float* b2 = (const float*)d_in[16];

    float* WS = (float*)d_ws;
    size_t avail = ws_size / 4;

    // bf16 residual stream: 2048*50*384 bf16 = 19,660,800 f32 slots
    const size_t OUT_FB = 19660800;
    const size_t WB_F   = 1769472;           // bf16 weights (f32 slots)
    const size_t BT_F   = 49152;             // bias table 12*64*64 fp32
    __hip_bfloat16* OUTB = (__hip_bfloat16*)WS;
    __hip_bfloat16* WB = (__hip_bfloat16*)(WS + OUT_FB);
    __hip_bfloat16* qwb = WB;                                   // 2*1152*384
    __hip_bfloat16* pwb = WB + 884736;                          // 2*384*384
    __hip_bfloat16* w1b = WB + 1179648;                         // 2*1536*384
    __hip_bfloat16* w2b = WB + 2359296;                         // 2*384*1536
    float* biasTbuf = WS + OUT_FB + WB_F;

    // cw = 1024. cw*NTT must be a multiple of 256 (cw >= 128).
    int cw = 1024;
    while (cw > 128 && OUT_FB + WB_F + BT_F + (size_t)cw * 48000 > avail) cw >>= 1;
    float* fbase = WS + OUT_FB + WB_F + BT_F;
    __hip_bfloat16* Xb = (__hip_bfloat16*)fbase;
    __hip_bfloat16* Qb = (__hip_bfloat16*)(fbase + (size_t)cw * 9600);
    __hip_bfloat16* Hb = Qb;   // MLP hidden reuses Qb region
    const float scale = 0.17677669529663687f;

    f2bf_kernel<<<dim3((884736 / 4 + 255) / 256), dim3(256), 0, stream>>>(qkv_w, qwb, 884736);
    f2bf_kernel<<<dim3((294912 / 4 + 255) / 256), dim3(256), 0, stream>>>(proj_w, pwb, 294912);
    f2bf_kernel<<<dim3((1179648 / 4 + 255) / 256), dim3(256), 0, stream>>>(w1, w1b, 1179648);
    f2bf_kernel<<<dim3((1179648 / 4 + 255) / 256), dim3(256), 0, stream>>>(w2, w2b, 1179648);

    pack_cls_kernel<<<dim3(BB * 6), dim3(256), 0, stream>>>(cls_in, OUTB);
    pack_patch_kernel<<<dim3(BB * 56 * 6), dim3(256), 0, stream>>>(patch_in, OUTB);

    for (int i = 0; i < NBB; ++i) {
        const __hip_bfloat16* qw = qwb + (size_t)i * N3 * CC;
        const float* qb = qkv_b + (size_t)i * N3;
        const __hip_bfloat16* pw = pwb + (size_t)i * CC * CC;
        const float* pb = proj_b + (size_t)i * CC;
        const float* rp = rel_pos + (size_t)i * NHH * 169;
        const __hip_bfloat16* w1i = w1b + (size_t)i * HIDD * CC;
        const float* b1i = b1 + (size_t)i * HIDD;
        const __hip_bfloat16* w2i = w2b + (size_t)i * CC * HIDD;
        const float* b2i = b2 + (size_t)i * CC;

        bias_precompute_kernel<<<dim3(NHH), dim3(256), 0, stream>>>(rp, biasTbuf);

        // ---- stage A: cls attention across 64 windows of each image (T=64) ----
        ln_kernel<<<dim3(2048 / 4), dim3(256), 0, stream>>>(OUTB, LDOUT, ln0w + i * CC, ln0b + i * CC, Xb, CC, 2048);
        gemm_bf16_kernel<1, 0, 0, CC><<<dim3((N3 / 128) * (2048 / 256)), dim3(512), 0, stream>>>(
            Xb, CC, qw, qb, Qb, N3, 2048, N3, N3 / 128);
        attn_mfma_kernel<<<dim3(BB * 3), dim3(256), 0, stream>>>(Qb, nullptr, Xb, 64, scale, BB);
        gemm_bf16_kernel<1, 0, 1, CC><<<dim3((CC / 128) * (2048 / 256)), dim3(512), 0, stream>>>(
            Xb, CC, pw, pb, OUTB, LDOUT, 2048, CC, CC / 128);

        // ---- stage B: windowed attention with rel-pos bias (T=50) ----
        for (int w0 = 0; w0 < NWW; w0 += cw) {
            __hip_bfloat16* outc = OUTB + (size_t)w0 * LDOUT;
            int Mr = cw * NTT;
            ln_kernel<<<dim3(Mr / 4), dim3(256), 0, stream>>>(outc, CC, ln1w + i * CC, ln1b + i * CC, Xb, CC, Mr);
            gemm_bf16_kernel<1, 0, 0, CC><<<dim3((N3 / 128) * (Mr / 256)), dim3(512), 0, stream>>>(
                Xb, CC, qw, qb, Qb, N3, Mr, N3, N3 / 128);
            attn_mfma_kernel<<<dim3(cw * 3), dim3(256), 0, stream>>>(Qb, biasTbuf, Xb, NTT, scale, cw);
            gemm_bf16_kernel<1, 0, 1, CC><<<dim3((CC / 128) * (Mr / 256)), dim3(512), 0, stream>>>(
                Xb, CC, pw, pb, outc, CC, Mr, CC, CC / 128);
        }

        // ---- stage C: MLP ----
        for (int w0 = 0; w0 < NWW; w0 += cw) {
            __hip_bfloat16* outc = OUTB + (size_t)w0 * LDOUT;
            int Mr = cw * NTT;
            ln_kernel<<<dim3(Mr / 4), dim3(256), 0, stream>>>(outc, CC, ln2w + i * CC, ln2b + i * CC, Xb, CC, Mr);
            gemm_bf16_kernel<1, 1, 0, CC><<<dim3((HIDD / 128) * (Mr / 256)), dim3(512), 0, stream>>>(
                Xb, CC, w1i, b1i, Hb, HIDD, Mr, HIDD, HIDD / 128);
            gemm_bf16_kernel<1, 0, 1, HIDD><<<dim3((CC / 128) * (Mr / 256)), dim3(512), 0, stream>>>(
                Hb, HIDD, w2i, b2i, outc, CC, Mr, CC, CC / 128);
        }
    }

    unpack_cls_kernel<<<dim3(BB * 6), dim3(256), 0, stream>>>(OUTB, (float*)d_out);
    unpack_patch_kernel<<<dim3(BB * 56 * 6), dim3(256), 0, stream>>>(OUTB, (float*)d_out + 786432);
}

// Round 16
// 1711.332 us; speedup vs baseline: 1.1972x; 1.0391x over previous
//
#include <hip/hip_runtime.h>
#include <hip/hip_bf16.h>
#include <cstdint>
#include <cstddef>

// ---- problem constants ----
#define BB    32
#define CC    384
#define NHH   12
#define HDD   32
#define WSS   7
#define HKK   8
#define NBB   2
#define HIDD  1536
#define NTT   50          // tokens per window (1 cls + 49 patch)
#define NWW   2048        // B*HK*HK windows
#define LDOUT 19200       // 50*384
#define N3    1152        // 3*C

typedef __attribute__((ext_vector_type(8))) short short8v;
typedef __attribute__((ext_vector_type(4))) float f32x4;

#if defined(__has_builtin)
#if __has_builtin(__builtin_amdgcn_global_load_lds)
#define HAS_GLDS 1
#endif
#endif
#ifndef HAS_GLDS
#define HAS_GLDS 0
#endif

// sigmoid-form GELU with hardware-rcp: x*sigmoid(1.702x).
// v_rcp_f32 (~1 ULP) replaces the IEEE div sequence (~10 VALU ops) --
// error << bf16 quantum. Total: 3 VALU + 2 transcendental.
static __device__ __forceinline__ float gelu_f(float x) {
    float e = __expf(-1.702f * x);
    return x * __builtin_amdgcn_rcpf(1.0f + e);
}

static __device__ __forceinline__ short bf16s(float x) {
    __hip_bfloat16 b = __float2bfloat16(x);
    return *(short*)&b;
}

static __device__ __forceinline__ float bf2f(short s) {
    union { unsigned int u; float f; } cv;
    cv.u = ((unsigned int)(unsigned short)s) << 16;
    return cv.f;
}

#if HAS_GLDS
static __device__ __forceinline__ void glds16(const short* g, short* l) {
    __builtin_amdgcn_global_load_lds(
        (const __attribute__((address_space(1))) unsigned int*)g,
        (__attribute__((address_space(3))) unsigned int*)l,
        16, 0, 0);
}
#endif

// XCD-aware decode: keep all nx column-blocks of one row-panel on ONE XCD.
static __device__ __forceinline__ void swz_decode(int L, int nx, int ny, int& bx, int& by) {
    if (ny & 7) {
        bx = L % nx; by = L / nx;
    } else {
        int r = L & 7, pos = L >> 3;
        bx = pos % nx;
        by = (pos / nx) * 8 + r;
    }
}

// ---------------- pack / unpack (fp32 <-> bf16 residual stream) ----------------
__global__ void pack_cls_kernel(const float* __restrict__ cls, __hip_bfloat16* __restrict__ out) {
    __shared__ float lds[64][65];
    int bid = blockIdx.x;
    int b = bid / 6, cc = bid % 6, c0 = cc * 64;
    int tid = threadIdx.x;
    for (int idx = tid; idx < 64 * 64; idx += 256) {
        int k = idx & 63, cl = idx >> 6;
        lds[cl][k] = cls[((size_t)b * CC + c0 + cl) * 64 + k];
    }
    __syncthreads();
    short* ob = (short*)out;
    for (int idx = tid; idx < 64 * 64; idx += 256) {
        int cl = idx & 63, k = idx >> 6;
        ob[(size_t)(b * 64 + k) * LDOUT + c0 + cl] = bf16s(lds[cl][k]);
    }
}

__global__ void pack_patch_kernel(const float* __restrict__ patch, __hip_bfloat16* __restrict__ out) {
    __shared__ float lds[64][57];
    int bid = blockIdx.x;
    int b = bid / 336, rem = bid % 336;
    int y = rem / 6, cc = rem % 6, c0 = cc * 64;
    int tid = threadIdx.x;
    for (int idx = tid; idx < 64 * 56; idx += 256) {
        int cl = idx / 56, x = idx % 56;
        lds[cl][x] = patch[(((size_t)b * CC + c0 + cl) * 56 + y) * 56 + x];
    }
    __syncthreads();
    int wsy = y % 7, hky = y / 7;
    short* ob = (short*)out;
    for (int idx = tid; idx < 64 * 56; idx += 256) {
        int cl = idx & 63, x = idx >> 6;
        int tok = 1 + wsy * 7 + (x % 7);
        int win = b * 64 + hky * 8 + (x / 7);
        ob[((size_t)win * NTT + tok) * CC + c0 + cl] = bf16s(lds[cl][x]);
    }
}

__global__ void unpack_cls_kernel(const __hip_bfloat16* __restrict__ out, float* __restrict__ cls_out) {
    __shared__ float lds[64][65];
    int bid = blockIdx.x;
    int b = bid / 6, cc = bid % 6, c0 = cc * 64;
    int tid = threadIdx.x;
    const short* ob = (const short*)out;
    for (int idx = tid; idx < 64 * 64; idx += 256) {
        int cl = idx & 63, k = idx >> 6;
        lds[cl][k] = bf2f(ob[(size_t)(b * 64 + k) * LDOUT + c0 + cl]);
    }
    __syncthreads();
    for (int idx = tid; idx < 64 * 64; idx += 256) {
        int k = idx & 63, cl = idx >> 6;
        cls_out[((size_t)b * CC + c0 + cl) * 64 + k] = lds[cl][k];
    }
}

__global__ void unpack_patch_kernel(const __hip_bfloat16* __restrict__ out, float* __restrict__ patch_out) {
    __shared__ float lds[64][57];
    int bid = blockIdx.x;
    int b = bid / 336, rem = bid % 336;
    int y = rem / 6, cc = rem % 6, c0 = cc * 64;
    int tid = threadIdx.x;
    int wsy = y % 7, hky = y / 7;
    const short* ob = (const short*)out;
    for (int idx = tid; idx < 64 * 56; idx += 256) {
        int cl = idx & 63, x = idx >> 6;
        int tok = 1 + wsy * 7 + (x % 7);
        int win = b * 64 + hky * 8 + (x / 7);
        lds[cl][x] = bf2f(ob[((size_t)win * NTT + tok) * CC + c0 + cl]);
    }
    __syncthreads();
    for (int idx = tid; idx < 64 * 56; idx += 256) {
        int cl = idx / 56, x = idx % 56;
        patch_out[((size_t)b * CC + c0 + cl) * 3136 + y * 56 + x] = lds[cl][x];
    }
}

// ---------------- fp32 -> bf16 weight conversion ----------------
__global__ void f2bf_kernel(const float* __restrict__ in, __hip_bfloat16* __restrict__ out, int n) {
    int i = (blockIdx.x * 256 + threadIdx.x) * 4;
    if (i + 3 < n) {
        float4 v = *(const float4*)(in + i);
        out[i + 0] = __float2bfloat16(v.x);
        out[i + 1] = __float2bfloat16(v.y);
        out[i + 2] = __float2bfloat16(v.z);
        out[i + 3] = __float2bfloat16(v.w);
    } else {
        for (; i < n; ++i) out[i] = __float2bfloat16(in[i]);
    }
}

// ---------------- rel-pos bias table, fragment-ordered: [12][64 r][16 lc][4 n] fp32 ----------------
__global__ void bias_precompute_kernel(const float* __restrict__ rp, float* __restrict__ biasT) {
    int h = blockIdx.x;
    for (int idx = threadIdx.x; idx < 4096; idx += 256) {
        int qt = idx >> 6, kt = idx & 63;
        float v = 0.f;
        if (qt >= 1 && qt < NTT && kt >= 1 && kt < NTT) {
            int qp = qt - 1, kp = kt - 1;
            int qy = qp / 7, qx = qp - qy * 7;
            int ky = kp / 7, kx = kp - ky * 7;
            int ridx = ((ky - qy + 16) % 13) * 13 + ((kx - qx + 16) % 13);
            v = rp[h * 169 + ridx];
        }
        biasT[h * 4096 + qt * 64 + (kt & 15) * 4 + (kt >> 4)] = v;
    }
}

// ---------------- LayerNorm (bf16 in) -> bf16 out ----------------
__global__ void ln_kernel(const __hip_bfloat16* __restrict__ x, int ldx,
                          const float* __restrict__ w, const float* __restrict__ b,
                          __hip_bfloat16* __restrict__ y, int ldy, int M) {
    int wave = threadIdx.x >> 6, lane = threadIdx.x & 63;
    int row = blockIdx.x * 4 + wave;
    if (row >= M) return;
    const ushort2* xr = (const ushort2*)((const short*)x + (size_t)row * ldx);
    float2 vals[3];
    float s = 0.f;
#pragma unroll
    for (int j = 0; j < 3; ++j) {
        ushort2 u = xr[lane + j * 64];
        vals[j].x = bf2f((short)u.x);
        vals[j].y = bf2f((short)u.y);
        s += vals[j].x + vals[j].y;
    }
#pragma unroll
    for (int off = 32; off > 0; off >>= 1) s += __shfl_xor(s, off);
    float mean = s * (1.0f / 384.0f);
    float vs = 0.f;
#pragma unroll
    for (int j = 0; j < 3; ++j) {
        float dx = vals[j].x - mean, dy = vals[j].y - mean;
        vs += dx * dx + dy * dy;
    }
#pragma unroll
    for (int off = 32; off > 0; off >>= 1) vs += __shfl_xor(vs, off);
    float inv = rsqrtf(vs * (1.0f / 384.0f) + 1e-6f);
    const float2* w2 = (const float2*)w;
    const float2* b2 = (const float2*)b;
    ushort* yr = (ushort*)y + (size_t)row * ldy;
#pragma unroll
    for (int j = 0; j < 3; ++j) {
        int c = lane + j * 64;
        float2 wv = w2[c], bv = b2[c];
        ushort2 o;
        o.x = (ushort)bf16s((vals[j].x - mean) * inv * wv.x + bv.x);
        o.y = (ushort)bf16s((vals[j].y - mean) * inv * wv.y + bv.y);
        *(ushort2*)(yr + c * 2) = o;
    }
}

// ---------------- bf16 MFMA GEMM v7: Y = A[M,K] @ W[N,K]^T ----------------
// Best-measured structure: 256x128 tile, 8 waves (4M x 2N), BK=32,
// 3-slot ring (72 KB -> 2 blocks/CU), counted-vmcnt depth-2 (6/3/0),
// both-sides XOR bank swizzle (R14: conflicts 8.6M -> 1.2M), compile-time K
// fully-unrolled K-loop (R15: staging addrs fold to immediates).
// launch_bounds(512,4) (R10 lesson: never under-budget the accumulator).
template <int BIAS, int GELU, int ACC, int KT>
__global__ __launch_bounds__(512, 4) void gemm_bf16_kernel(
    const __hip_bfloat16* __restrict__ A, int lda,
    const __hip_bfloat16* __restrict__ W,
    const float* __restrict__ bias,
    __hip_bfloat16* __restrict__ Yb, int ldyb,
    int M, int N, int nx) {
    __shared__ __align__(16) union SMemU {
        struct { short As[3][256 * 32]; short Bs[3][128 * 32]; } st;  // 72 KB ring
        short obf[256][132];   // 67.6 KB bf16 output tile
    } sm;
    int tid = threadIdx.x;
    int lane = tid & 63;
    int wid = tid >> 6;               // 0..7
    int wr = wid >> 1, wc = wid & 1;  // wr: 64-row band (0..3), wc: 64-col band (0..1)
    int bx, by;
    swz_decode(blockIdx.x, nx, M >> 8, bx, by);
    int row0 = by * 256, col0 = bx * 128;

    // staging: wave wid covers A rows [wid*32, +32) (2 glds) and B rows
    // [wid*16, +16) (1 glds). lane -> row = lane>>2, SWIZZLED source group.
    int sgrp = ((lane & 3) ^ ((lane >> 3) & 3)) * 8;   // swizzled source col (elems)
    const short* Ag = (const short*)A + (size_t)(row0 + wid * 32 + (lane >> 2)) * lda + sgrp;
    const short* Wg = (const short*)W + (size_t)(col0 + wid * 16 + (lane >> 2)) * KT + sgrp;
    size_t astep16 = (size_t)16 * lda;
    int ldsA = wid * 32 * 32;   // wave-uniform element offsets; HW adds lane*16B
    int ldsB = wid * 16 * 32;

#if HAS_GLDS
#define STAGE(buf, k0)                                                \
    do {                                                              \
        glds16(Ag + (k0), &sm.st.As[buf][ldsA]);                      \
        glds16(Ag + astep16 + (k0), &sm.st.As[buf][ldsA + 16 * 32]);  \
        glds16(Wg + (k0), &sm.st.Bs[buf][ldsB]);                      \
    } while (0)
#else
#define STAGE(buf, k0)                                                               \
    do {                                                                             \
        *(short8v*)(&sm.st.As[buf][ldsA] + lane * 8) = *(const short8v*)(Ag + (k0)); \
        *(short8v*)(&sm.st.As[buf][ldsA + 16 * 32] + lane * 8) = *(const short8v*)(Ag + astep16 + (k0)); \
        *(short8v*)(&sm.st.Bs[buf][ldsB] + lane * 8) = *(const short8v*)(Wg + (k0)); \
    } while (0)
#endif

    f32x4 acc[4][4] = {};
    int frow_a = wr * 64 + (lane & 15);
    int frow_b = wc * 64 + (lane & 15);
    // swizzled fragment k-offset (elements): gk ^ ((row>>1)&3); row mod-4 term
    // depends only on lane&15 (band/f contributions are 0 mod 4 after >>1).
    int fks = (((lane >> 4) ^ (((lane & 15) >> 1) & 3)) * 8);

    constexpr int nt = KT >> 5;
#if HAS_GLDS
    // counted-vmcnt pipeline, depth 2, 3 slots; fully unrolled (KT constexpr).
    STAGE(0, 0);
    if (nt > 1) STAGE(1, 32);
#pragma unroll
    for (int t = 0; t < nt; ++t) {
        const int sc = t % 3;
        const int sn = (t + 2) % 3;
        if (t + 2 < nt) {
            STAGE(sn, (t + 2) << 5);
            asm volatile("s_waitcnt vmcnt(6)" ::: "memory");
        } else if (t + 1 < nt) {
            asm volatile("s_waitcnt vmcnt(3)" ::: "memory");
        } else {
            asm volatile("s_waitcnt vmcnt(0)" ::: "memory");
        }
        __builtin_amdgcn_s_barrier();          // A: everyone's tile-t loads landed
        __builtin_amdgcn_sched_barrier(0);
        short8v a[4], b[4];
#pragma unroll
        for (int m = 0; m < 4; ++m) a[m] = *(const short8v*)&sm.st.As[sc][(frow_a + m * 16) * 32 + fks];
#pragma unroll
        for (int n = 0; n < 4; ++n) b[n] = *(const short8v*)&sm.st.Bs[sc][(frow_b + n * 16) * 32 + fks];
        __builtin_amdgcn_s_setprio(1);
#pragma unroll
        for (int m = 0; m < 4; ++m)
#pragma unroll
            for (int n = 0; n < 4; ++n)
                acc[m][n] = __builtin_amdgcn_mfma_f32_16x16x32_bf16(a[m], b[n], acc[m][n], 0, 0, 0);
        __builtin_amdgcn_s_setprio(0);
        __builtin_amdgcn_sched_barrier(0);
        __builtin_amdgcn_s_barrier();          // B: all waves consumed tile t
    }
#else
    STAGE(0, 0);
    __syncthreads();
#pragma unroll
    for (int t = 0; t < nt; ++t) {
        const int cur = t & 1;
        if (t + 1 < nt) STAGE(cur ^ 1, (t + 1) << 5);
        short8v a[4], b[4];
#pragma unroll
        for (int m = 0; m < 4; ++m) a[m] = *(const short8v*)&sm.st.As[cur][(frow_a + m * 16) * 32 + fks];
#pragma unroll
        for (int n = 0; n < 4; ++n) b[n] = *(const short8v*)&sm.st.Bs[cur][(frow_b + n * 16) * 32 + fks];
#pragma unroll
        for (int m = 0; m < 4; ++m)
#pragma unroll
            for (int n = 0; n < 4; ++n)
                acc[m][n] = __builtin_amdgcn_mfma_f32_16x16x32_bf16(a[m], b[n], acc[m][n], 0, 0, 0);
        if (t + 1 < nt) __syncthreads();
    }
#endif
#undef STAGE

    // ---- epilogue: LDS-staged coalesced bf16 stores (ACC: RMW during store) ----
    __syncthreads();   // staging ring dead; overlay output buffer
    int lr = (lane >> 4) * 4;
    int lc = lane & 15;
#pragma unroll
    for (int n = 0; n < 4; ++n) {
        int c = wc * 64 + n * 16 + lc;
        float bv = BIAS ? bias[col0 + c] : 0.0f;
#pragma unroll
        for (int m = 0; m < 4; ++m) {
#pragma unroll
            for (int j = 0; j < 4; ++j) {
                float v = acc[m][n][j] + bv;
                if (GELU) v = gelu_f(v);
                sm.obf[wr * 64 + m * 16 + lr + j][c] = bf16s(v);
            }
        }
    }
    __syncthreads();
    short* yb = (short*)Yb + (size_t)row0 * ldyb + col0;
#pragma unroll
    for (int it = 0; it < 8; ++it) {
        int r = (tid >> 4) + it * 32;
        int c8 = (tid & 15) * 8;
        short8v v = *(const short8v*)&sm.obf[r][c8];
        short* yp = yb + (size_t)r * ldyb + c8;
        if (ACC) {
            short8v o = *(const short8v*)yp;
#pragma unroll
            for (int e = 0; e < 8; ++e) v[e] = bf16s(bf2f(v[e]) + bf2f(o[e]));
        }
        *(short8v*)yp = v;
    }
}

// ---------------- MFMA attention, barrier-free, XCD-swizzled ----------------
__global__ __launch_bounds__(256) void attn_mfma_kernel(
    const __hip_bfloat16* __restrict__ qkv,
    const float* __restrict__ biasT,
    __hip_bfloat16* __restrict__ o,
    int T, float scale, int nwin) {
    __shared__ __align__(16) short Vt[4][32][72];   // [wave][d][kt]  (V transposed)
    __shared__ __align__(16) short Pl[4][64][40];   // [wave][r][half-K cols]
    const int tid = threadIdx.x, lane = tid & 63, wv = tid >> 6;
    int p, hg;
    {
        int L = blockIdx.x;
        if (nwin & 7) { hg = L % 3; p = L / 3; }
        else { int r = L & 7, pos = L >> 3; hg = pos % 3; p = (pos / 3) * 8 + r; }
    }
    const int h = hg * 4 + wv;
    const short* q_base = (const short*)qkv + (size_t)p * T * N3;

    const int fr = lane & 15;
    const int fk = (lane >> 4) * 8;
    const int lg = lane >> 4;
    const int lc = lane & 15;

    short8v aq[4], bk[4];
#pragma unroll
    for (int m = 0; m < 4; ++m) {
        const short* qp = q_base + (size_t)(m * 16 + fr) * N3 + h * 32 + fk;
        aq[m] = *(const short8v*)qp;
        bk[m] = *(const short8v*)(qp + 384);
    }

    for (int ch = lane; ch < T * 4; ch += 64) {
        int t = ch >> 2, cq = ch & 3;
        short8v v8 = *(const short8v*)(q_base + (size_t)t * N3 + 768 + h * 32 + cq * 8);
#pragma unroll
        for (int e = 0; e < 8; ++e) Vt[wv][cq * 8 + e][t] = v8[e];
    }
    for (int idx = lane; idx < (64 - T) * 32; idx += 64) {
        int t = T + (idx >> 5), d = idx & 31;
        Vt[wv][d][t] = 0;
    }

    f32x4 acc[4][4] = {};
#pragma unroll
    for (int m = 0; m < 4; ++m)
#pragma unroll
        for (int n = 0; n < 4; ++n)
            acc[m][n] = __builtin_amdgcn_mfma_f32_16x16x32_bf16(aq[m], bk[n], acc[m][n], 0, 0, 0);

    const float* bh = biasT ? (biasT + (size_t)h * 4096) : nullptr;
    float p2[4][4], p3[4][4];
#pragma unroll
    for (int m = 0; m < 4; ++m) {
#pragma unroll
        for (int j = 0; j < 4; ++j) {
            int r = m * 16 + lg * 4 + j;
            float v[4];
            if (bh) {
                float4 bv4 = *(const float4*)(bh + r * 64 + lc * 4);
#pragma unroll
                for (int n = 0; n < 4; ++n) v[n] = acc[m][n][j] * scale + ((const float*)&bv4)[n];
            } else {
#pragma unroll
                for (int n = 0; n < 4; ++n) v[n] = acc[m][n][j] * scale;
            }
#pragma unroll
            for (int n = 0; n < 4; ++n)
                if (n * 16 + lc >= T) v[n] = -1e30f;
            float mx = fmaxf(fmaxf(v[0], v[1]), fmaxf(v[2], v[3]));
#pragma unroll
            for (int off = 1; off < 16; off <<= 1) mx = fmaxf(mx, __shfl_xor(mx, off));
            float s = 0.f;
#pragma unroll
            for (int n = 0; n < 4; ++n) { v[n] = __expf(v[n] - mx); s += v[n]; }
#pragma unroll
            for (int off = 1; off < 16; off <<= 1) s += __shfl_xor(s, off);
            float inv = 1.0f / s;
            Pl[wv][r][lc]      = bf16s(v[0] * inv);
            Pl[wv][r][16 + lc] = bf16s(v[1] * inv);
            p2[m][j] = v[2] * inv;
            p3[m][j] = v[3] * inv;
        }
    }

    f32x4 oacc[4][2] = {};
    {
        short8v ap[4], bv[2];
#pragma unroll
        for (int m = 0; m < 4; ++m) ap[m] = *(const short8v*)&Pl[wv][m * 16 + fr][fk];
#pragma unroll
        for (int n = 0; n < 2; ++n) bv[n] = *(const short8v*)&Vt[wv][n * 16 + fr][fk];
#pragma unroll
        for (int m = 0; m < 4; ++m)
#pragma unroll
            for (int n = 0; n < 2; ++n)
                oacc[m][n] = __builtin_amdgcn_mfma_f32_16x16x32_bf16(ap[m], bv[n], oacc[m][n], 0, 0, 0);
    }
#pragma unroll
    for (int m = 0; m < 4; ++m)
#pragma unroll
        for (int j = 0; j < 4; ++j) {
            int r = m * 16 + lg * 4 + j;
            Pl[wv][r][lc]      = bf16s(p2[m][j]);
            Pl[wv][r][16 + lc] = bf16s(p3[m][j]);
        }
    {
        short8v ap[4], bv[2];
#pragma unroll
        for (int m = 0; m < 4; ++m) ap[m] = *(const short8v*)&Pl[wv][m * 16 + fr][fk];
#pragma unroll
        for (int n = 0; n < 2; ++n) bv[n] = *(const short8v*)&Vt[wv][n * 16 + fr][32 + fk];
#pragma unroll
        for (int m = 0; m < 4; ++m)
#pragma unroll
            for (int n = 0; n < 2; ++n)
                oacc[m][n] = __builtin_amdgcn_mfma_f32_16x16x32_bf16(ap[m], bv[n], oacc[m][n], 0, 0, 0);
    }

    short* ob = (short*)o;
#pragma unroll
    for (int m = 0; m < 4; ++m)
#pragma unroll
        for (int j = 0; j < 4; ++j) {
            int r = m * 16 + lg * 4 + j;
            if (r < T) {
#pragma unroll
                for (int n = 0; n < 2; ++n)
                    ob[((size_t)p * T + r) * CC + h * 32 + n * 16 + lc] = bf16s(oacc[m][n][j]);
            }
        }
}

// ---------------- host ----------------
extern "C" void kernel_launch(void* const* d_in, const int* in_sizes, int n_in,
                              void* d_out, int out_size, void* d_ws, size_t ws_size,
                              hipStream_t stream) {
    const float* cls_in   = (const float*)d_in[0];
    const float* patch_in = (const float*)d_in[1];
    const float* qkv_w    = (const float*)d_in[2];
    const float* qkv_b    = (const float*)d_in[3];
    const float* proj_w   = (const float*)d_in[4];
    const float* proj_b   = (const float*)d_in[5];
    const float* rel_pos  = (const float*)d_in[6];
    const float* ln0w = (const float*)d_in[7];
    const float* ln0b = (const float*)d_in[8];
    const float* ln1w = (const float*)d_in[9];
    const float* ln1b = (const float*)d_in[10];
    const float* ln2w = (const float*)d_in[11];
    const float* ln2b = (const float*)d_in[12];
    const float* w1 = (const float*)d_in[13];
    const float* b1 = (const float*)d_in[14];
    const float* w2 = (const float*)d_in[15];
    const float* b2 = (const float*)d_in[16];

    float* WS = (float*)d_ws;
    size_t avail = ws_size / 4;

    // bf16 residual stream: 2048*50*384 bf16 = 19,660,800 f32 slots
    const size_t OUT_FB = 19660800;
    const size_t WB_F   = 1769472;           // bf16 weights (f32 slots)
    const size_t BT_F   = 49152;             // bias table 12*64*64 fp32
    __hip_bfloat16* OUTB = (__hip_bfloat16*)WS;
    __hip_bfloat16* WB = (__hip_bfloat16*)(WS + OUT_FB);
    __hip_bfloat16* qwb = WB;                                   // 2*1152*384
    __hip_bfloat16* pwb = WB + 884736;                          // 2*384*384
    __hip_bfloat16* w1b = WB + 1179648;                         // 2*1536*384
    __hip_bfloat16* w2b = WB + 2359296;                         // 2*384*1536
    float* biasTbuf = WS + OUT_FB + WB_F;

    // cw = 2048: halves stage-B/C dispatch count (launch/tail overhead).
    // cw*NTT must be a multiple of 256 (cw >= 128).
    int cw = 2048;
    while (cw > 128 && OUT_FB + WB_F + BT_F + (size_t)cw * 48000 > avail) cw >>= 1;
    float* fbase = WS + OUT_FB + WB_F + BT_F;
    __hip_bfloat16* Xb = (__hip_bfloat16*)fbase;
    __hip_bfloat16* Qb = (__hip_bfloat16*)(fbase + (size_t)cw * 9600);
    __hip_bfloat16* Hb = Qb;   // MLP hidden reuses Qb region
    const float scale = 0.17677669529663687f;

    f2bf_kernel<<<dim3((884736 / 4 + 255) / 256), dim3(256), 0, stream>>>(qkv_w, qwb, 884736);
    f2bf_kernel<<<dim3((294912 / 4 + 255) / 256), dim3(256), 0, stream>>>(proj_w, pwb, 294912);
    f2bf_kernel<<<dim3((1179648 / 4 + 255) / 256), dim3(256), 0, stream>>>(w1, w1b, 1179648);
    f2bf_kernel<<<dim3((1179648 / 4 + 255) / 256), dim3(256), 0, stream>>>(w2, w2b, 1179648);

    pack_cls_kernel<<<dim3(BB * 6), dim3(256), 0, stream>>>(cls_in, OUTB);
    pack_patch_kernel<<<dim3(BB * 56 * 6), dim3(256), 0, stream>>>(patch_in, OUTB);

    for (int i = 0; i < NBB; ++i) {
        const __hip_bfloat16* qw = qwb + (size_t)i * N3 * CC;
        const float* qb = qkv_b + (size_t)i * N3;
        const __hip_bfloat16* pw = pwb + (size_t)i * CC * CC;
        const float* pb = proj_b + (size_t)i * CC;
        const float* rp = rel_pos + (size_t)i * NHH * 169;
        const __hip_bfloat16* w1i = w1b + (size_t)i * HIDD * CC;
        const float* b1i = b1 + (size_t)i * HIDD;
        const __hip_bfloat16* w2i = w2b + (size_t)i * CC * HIDD;
        const float* b2i = b2 + (size_t)i * CC;

        bias_precompute_kernel<<<dim3(NHH), dim3(256), 0, stream>>>(rp, biasTbuf);

        // ---- stage A: cls attention across 64 windows of each image (T=64) ----
        ln_kernel<<<dim3(2048 / 4), dim3(256), 0, stream>>>(OUTB, LDOUT, ln0w + i * CC, ln0b + i * CC, Xb, CC, 2048);
        gemm_bf16_kernel<1, 0, 0, CC><<<dim3((N3 / 128) * (2048 / 256)), dim3(512), 0, stream>>>(
            Xb, CC, qw, qb, Qb, N3, 2048, N3, N3 / 128);
        attn_mfma_kernel<<<dim3(BB * 3), dim3(256), 0, stream>>>(Qb, nullptr, Xb, 64, scale, BB);
        gemm_bf16_kernel<1, 0, 1, CC><<<dim3((CC / 128) * (2048 / 256)), dim3(512), 0, stream>>>(
            Xb, CC, pw, pb, OUTB, LDOUT, 2048, CC, CC / 128);

        // ---- stage B: windowed attention with rel-pos bias (T=50) ----
        for (int w0 = 0; w0 < NWW; w0 += cw) {
            __hip_bfloat16* outc = OUTB + (size_t)w0 * LDOUT;
            int Mr = cw * NTT;
            ln_kernel<<<dim3(Mr / 4), dim3(256), 0, stream>>>(outc, CC, ln1w + i * CC, ln1b + i * CC, Xb, CC, Mr);
            gemm_bf16_kernel<1, 0, 0, CC><<<dim3((N3 / 128) * (Mr / 256)), dim3(512), 0, stream>>>(
                Xb, CC, qw, qb, Qb, N3, Mr, N3, N3 / 128);
            attn_mfma_kernel<<<dim3(cw * 3), dim3(256), 0, stream>>>(Qb, biasTbuf, Xb, NTT, scale, cw);
            gemm_bf16_kernel<1, 0, 1, CC><<<dim3((CC / 128) * (Mr / 256)), dim3(512), 0, stream>>>(
                Xb, CC, pw, pb, outc, CC, Mr, CC, CC / 128);
        }

        // ---- stage C: MLP ----
        for (int w0 = 0; w0 < NWW; w0 += cw) {
            __hip_bfloat16* outc = OUTB + (size_t)w0 * LDOUT;
            int Mr = cw * NTT;
            ln_kernel<<<dim3(Mr / 4), dim3(256), 0, stream>>>(outc, CC, ln2w + i * CC, ln2b + i * CC, Xb, CC, Mr);
            gemm_bf16_kernel<1, 1, 0, CC><<<dim3((HIDD / 128) * (Mr / 256)), dim3(512), 0, stream>>>(
                Xb, CC, w1i, b1i, Hb, HIDD, Mr, HIDD, HIDD / 128);
            gemm_bf16_kernel<1, 0, 1, HIDD><<<dim3((CC / 128) * (Mr / 256)), dim3(512), 0, stream>>>(
                Hb, HIDD, w2i, b2i, outc, CC, Mr, CC, CC / 128);
        }
    }

    unpack_cls_kernel<<<dim3(BB * 6), dim3(256), 0, stream>>>(OUTB, (float*)d_out);
    unpack_patch_kernel<<<dim3(BB * 56 * 6), dim3(256), 0, stream>>>(OUTB, (float*)d_out + 786432);
}

// Round 17
// 1671.623 us; speedup vs baseline: 1.2256x; 1.0238x over previous
//
#include <hip/hip_runtime.h>
#include <hip/hip_bf16.h>
#include <cstdint>
#include <cstddef>

// ---- problem constants ----
#define BB    32
#define CC    384
#define NHH   12
#define HDD   32
#define WSS   7
#define HKK   8
#define NBB   2
#define HIDD  1536
#define NTT   50          // tokens per window (1 cls + 49 patch)
#define NWW   2048        // B*HK*HK windows
#define LDOUT 19200       // 50*384
#define N3    1152        // 3*C

typedef __attribute__((ext_vector_type(8))) short short8v;
typedef __attribute__((ext_vector_type(4))) float f32x4;

#if defined(__has_builtin)
#if __has_builtin(__builtin_amdgcn_global_load_lds)
#define HAS_GLDS 1
#endif
#endif
#ifndef HAS_GLDS
#define HAS_GLDS 0
#endif

// sigmoid-form GELU with hardware-rcp: x*sigmoid(1.702x).
static __device__ __forceinline__ float gelu_f(float x) {
    float e = __expf(-1.702f * x);
    return x * __builtin_amdgcn_rcpf(1.0f + e);
}

static __device__ __forceinline__ short bf16s(float x) {
    __hip_bfloat16 b = __float2bfloat16(x);
    return *(short*)&b;
}

static __device__ __forceinline__ float bf2f(short s) {
    union { unsigned int u; float f; } cv;
    cv.u = ((unsigned int)(unsigned short)s) << 16;
    return cv.f;
}

#if HAS_GLDS
static __device__ __forceinline__ void glds16(const short* g, short* l) {
    __builtin_amdgcn_global_load_lds(
        (const __attribute__((address_space(1))) unsigned int*)g,
        (__attribute__((address_space(3))) unsigned int*)l,
        16, 0, 0);
}
#endif

// XCD-aware decode: keep all nx column-blocks of one row-panel on ONE XCD.
static __device__ __forceinline__ void swz_decode(int L, int nx, int ny, int& bx, int& by) {
    if (ny & 7) {
        bx = L % nx; by = L / nx;
    } else {
        int r = L & 7, pos = L >> 3;
        bx = pos % nx;
        by = (pos / nx) * 8 + r;
    }
}

// ---------------- pack / unpack (fp32 <-> bf16 residual stream) ----------------
__global__ void pack_cls_kernel(const float* __restrict__ cls, __hip_bfloat16* __restrict__ out) {
    __shared__ float lds[64][65];
    int bid = blockIdx.x;
    int b = bid / 6, cc = bid % 6, c0 = cc * 64;
    int tid = threadIdx.x;
    for (int idx = tid; idx < 64 * 64; idx += 256) {
        int k = idx & 63, cl = idx >> 6;
        lds[cl][k] = cls[((size_t)b * CC + c0 + cl) * 64 + k];
    }
    __syncthreads();
    short* ob = (short*)out;
    for (int idx = tid; idx < 64 * 64; idx += 256) {
        int cl = idx & 63, k = idx >> 6;
        ob[(size_t)(b * 64 + k) * LDOUT + c0 + cl] = bf16s(lds[cl][k]);
    }
}

__global__ void pack_patch_kernel(const float* __restrict__ patch, __hip_bfloat16* __restrict__ out) {
    __shared__ float lds[64][57];
    int bid = blockIdx.x;
    int b = bid / 336, rem = bid % 336;
    int y = rem / 6, cc = rem % 6, c0 = cc * 64;
    int tid = threadIdx.x;
    for (int idx = tid; idx < 64 * 56; idx += 256) {
        int cl = idx / 56, x = idx % 56;
        lds[cl][x] = patch[(((size_t)b * CC + c0 + cl) * 56 + y) * 56 + x];
    }
    __syncthreads();
    int wsy = y % 7, hky = y / 7;
    short* ob = (short*)out;
    for (int idx = tid; idx < 64 * 56; idx += 256) {
        int cl = idx & 63, x = idx >> 6;
        int tok = 1 + wsy * 7 + (x % 7);
        int win = b * 64 + hky * 8 + (x / 7);
        ob[((size_t)win * NTT + tok) * CC + c0 + cl] = bf16s(lds[cl][x]);
    }
}

__global__ void unpack_cls_kernel(const __hip_bfloat16* __restrict__ out, float* __restrict__ cls_out) {
    __shared__ float lds[64][65];
    int bid = blockIdx.x;
    int b = bid / 6, cc = bid % 6, c0 = cc * 64;
    int tid = threadIdx.x;
    const short* ob = (const short*)out;
    for (int idx = tid; idx < 64 * 64; idx += 256) {
        int cl = idx & 63, k = idx >> 6;
        lds[cl][k] = bf2f(ob[(size_t)(b * 64 + k) * LDOUT + c0 + cl]);
    }
    __syncthreads();
    for (int idx = tid; idx < 64 * 64; idx += 256) {
        int k = idx & 63, cl = idx >> 6;
        cls_out[((size_t)b * CC + c0 + cl) * 64 + k] = lds[cl][k];
    }
}

__global__ void unpack_patch_kernel(const __hip_bfloat16* __restrict__ out, float* __restrict__ patch_out) {
    __shared__ float lds[64][57];
    int bid = blockIdx.x;
    int b = bid / 336, rem = bid % 336;
    int y = rem / 6, cc = rem % 6, c0 = cc * 64;
    int tid = threadIdx.x;
    int wsy = y % 7, hky = y / 7;
    const short* ob = (const short*)out;
    for (int idx = tid; idx < 64 * 56; idx += 256) {
        int cl = idx & 63, x = idx >> 6;
        int tok = 1 + wsy * 7 + (x % 7);
        int win = b * 64 + hky * 8 + (x / 7);
        lds[cl][x] = bf2f(ob[((size_t)win * NTT + tok) * CC + c0 + cl]);
    }
    __syncthreads();
    for (int idx = tid; idx < 64 * 56; idx += 256) {
        int cl = idx / 56, x = idx % 56;
        patch_out[((size_t)b * CC + c0 + cl) * 3136 + y * 56 + x] = lds[cl][x];
    }
}

// ---------------- fp32 -> bf16 weight conversion ----------------
__global__ void f2bf_kernel(const float* __restrict__ in, __hip_bfloat16* __restrict__ out, int n) {
    int i = (blockIdx.x * 256 + threadIdx.x) * 4;
    if (i + 3 < n) {
        float4 v = *(const float4*)(in + i);
        out[i + 0] = __float2bfloat16(v.x);
        out[i + 1] = __float2bfloat16(v.y);
        out[i + 2] = __float2bfloat16(v.z);
        out[i + 3] = __float2bfloat16(v.w);
    } else {
        for (; i < n; ++i) out[i] = __float2bfloat16(in[i]);
    }
}

// ---------------- rel-pos bias table, fragment-ordered: [12][64 r][16 lc][4 n] fp32 ----------------
__global__ void bias_precompute_kernel(const float* __restrict__ rp, float* __restrict__ biasT) {
    int h = blockIdx.x;
    for (int idx = threadIdx.x; idx < 4096; idx += 256) {
        int qt = idx >> 6, kt = idx & 63;
        float v = 0.f;
        if (qt >= 1 && qt < NTT && kt >= 1 && kt < NTT) {
            int qp = qt - 1, kp = kt - 1;
            int qy = qp / 7, qx = qp - qy * 7;
            int ky = kp / 7, kx = kp - ky * 7;
            int ridx = ((ky - qy + 16) % 13) * 13 + ((kx - qx + 16) % 13);
            v = rp[h * 169 + ridx];
        }
        biasT[h * 4096 + qt * 64 + (kt & 15) * 4 + (kt >> 4)] = v;
    }
}

// ---------------- LayerNorm (bf16 in) -> bf16 out ----------------
__global__ void ln_kernel(const __hip_bfloat16* __restrict__ x, int ldx,
                          const float* __restrict__ w, const float* __restrict__ b,
                          __hip_bfloat16* __restrict__ y, int ldy, int M) {
    int wave = threadIdx.x >> 6, lane = threadIdx.x & 63;
    int row = blockIdx.x * 4 + wave;
    if (row >= M) return;
    const ushort2* xr = (const ushort2*)((const short*)x + (size_t)row * ldx);
    float2 vals[3];
    float s = 0.f;
#pragma unroll
    for (int j = 0; j < 3; ++j) {
        ushort2 u = xr[lane + j * 64];
        vals[j].x = bf2f((short)u.x);
        vals[j].y = bf2f((short)u.y);
        s += vals[j].x + vals[j].y;
    }
#pragma unroll
    for (int off = 32; off > 0; off >>= 1) s += __shfl_xor(s, off);
    float mean = s * (1.0f / 384.0f);
    float vs = 0.f;
#pragma unroll
    for (int j = 0; j < 3; ++j) {
        float dx = vals[j].x - mean, dy = vals[j].y - mean;
        vs += dx * dx + dy * dy;
    }
#pragma unroll
    for (int off = 32; off > 0; off >>= 1) vs += __shfl_xor(vs, off);
    float inv = rsqrtf(vs * (1.0f / 384.0f) + 1e-6f);
    const float2* w2 = (const float2*)w;
    const float2* b2 = (const float2*)b;
    ushort* yr = (ushort*)y + (size_t)row * ldy;
#pragma unroll
    for (int j = 0; j < 3; ++j) {
        int c = lane + j * 64;
        float2 wv = w2[c], bv = b2[c];
        ushort2 o;
        o.x = (ushort)bf16s((vals[j].x - mean) * inv * wv.x + bv.x);
        o.y = (ushort)bf16s((vals[j].y - mean) * inv * wv.y + bv.y);
        *(ushort2*)(yr + c * 2) = o;
    }
}

// ---------------- bf16 MFMA GEMM v8: Y = A[M,K] @ W[N,K]^T ----------------
// Best-measured structure: 256x128 tile, 8 waves (4M x 2N), BK=32,
// 3-slot ring (72 KB -> 2 blocks/CU), counted-vmcnt depth-2 (6/3/0),
// both-sides XOR bank swizzle (R14), compile-time-K unrolled loop (R15).
// NEW (T14 on the epilogue): ACC old-OUT reads issued right after the final
// barrier, consumed after the obf pack phase -- the ~300 VALU ops of
// bias/gelu/pack hide the L2/HBM latency instead of a serial end-stall.
// Issued after the loop's last vmcnt(0): counted-vmcnt ledger untouched.
// launch_bounds(512,4) (R10 lesson: never under-budget the accumulator).
template <int BIAS, int GELU, int ACC, int KT>
__global__ __launch_bounds__(512, 4) void gemm_bf16_kernel(
    const __hip_bfloat16* __restrict__ A, int lda,
    const __hip_bfloat16* __restrict__ W,
    const float* __restrict__ bias,
    __hip_bfloat16* __restrict__ Yb, int ldyb,
    int M, int N, int nx) {
    __shared__ __align__(16) union SMemU {
        struct { short As[3][256 * 32]; short Bs[3][128 * 32]; } st;  // 72 KB ring
        short obf[256][132];   // 67.6 KB bf16 output tile
    } sm;
    int tid = threadIdx.x;
    int lane = tid & 63;
    int wid = tid >> 6;               // 0..7
    int wr = wid >> 1, wc = wid & 1;  // wr: 64-row band (0..3), wc: 64-col band (0..1)
    int bx, by;
    swz_decode(blockIdx.x, nx, M >> 8, bx, by);
    int row0 = by * 256, col0 = bx * 128;

    // staging: wave wid covers A rows [wid*32, +32) (2 glds) and B rows
    // [wid*16, +16) (1 glds). lane -> row = lane>>2, SWIZZLED source group.
    int sgrp = ((lane & 3) ^ ((lane >> 3) & 3)) * 8;   // swizzled source col (elems)
    const short* Ag = (const short*)A + (size_t)(row0 + wid * 32 + (lane >> 2)) * lda + sgrp;
    const short* Wg = (const short*)W + (size_t)(col0 + wid * 16 + (lane >> 2)) * KT + sgrp;
    size_t astep16 = (size_t)16 * lda;
    int ldsA = wid * 32 * 32;   // wave-uniform element offsets; HW adds lane*16B
    int ldsB = wid * 16 * 32;

#if HAS_GLDS
#define STAGE(buf, k0)                                                \
    do {                                                              \
        glds16(Ag + (k0), &sm.st.As[buf][ldsA]);                      \
        glds16(Ag + astep16 + (k0), &sm.st.As[buf][ldsA + 16 * 32]);  \
        glds16(Wg + (k0), &sm.st.Bs[buf][ldsB]);                      \
    } while (0)
#else
#define STAGE(buf, k0)                                                               \
    do {                                                                             \
        *(short8v*)(&sm.st.As[buf][ldsA] + lane * 8) = *(const short8v*)(Ag + (k0)); \
        *(short8v*)(&sm.st.As[buf][ldsA + 16 * 32] + lane * 8) = *(const short8v*)(Ag + astep16 + (k0)); \
        *(short8v*)(&sm.st.Bs[buf][ldsB] + lane * 8) = *(const short8v*)(Wg + (k0)); \
    } while (0)
#endif

    f32x4 acc[4][4] = {};
    int frow_a = wr * 64 + (lane & 15);
    int frow_b = wc * 64 + (lane & 15);
    // swizzled fragment k-offset (elements): gk ^ ((row>>1)&3); row mod-4 term
    // depends only on lane&15 (band/f contributions are 0 mod 4 after >>1).
    int fks = (((lane >> 4) ^ (((lane & 15) >> 1) & 3)) * 8);

    constexpr int nt = KT >> 5;
#if HAS_GLDS
    // counted-vmcnt pipeline, depth 2, 3 slots; fully unrolled (KT constexpr).
    STAGE(0, 0);
    if (nt > 1) STAGE(1, 32);
#pragma unroll
    for (int t = 0; t < nt; ++t) {
        const int sc = t % 3;
        const int sn = (t + 2) % 3;
        if (t + 2 < nt) {
            STAGE(sn, (t + 2) << 5);
            asm volatile("s_waitcnt vmcnt(6)" ::: "memory");
        } else if (t + 1 < nt) {
            asm volatile("s_waitcnt vmcnt(3)" ::: "memory");
        } else {
            asm volatile("s_waitcnt vmcnt(0)" ::: "memory");
        }
        __builtin_amdgcn_s_barrier();          // A: everyone's tile-t loads landed
        __builtin_amdgcn_sched_barrier(0);
        short8v a[4], b[4];
#pragma unroll
        for (int m = 0; m < 4; ++m) a[m] = *(const short8v*)&sm.st.As[sc][(frow_a + m * 16) * 32 + fks];
#pragma unroll
        for (int n = 0; n < 4; ++n) b[n] = *(const short8v*)&sm.st.Bs[sc][(frow_b + n * 16) * 32 + fks];
        __builtin_amdgcn_s_setprio(1);
#pragma unroll
        for (int m = 0; m < 4; ++m)
#pragma unroll
            for (int n = 0; n < 4; ++n)
                acc[m][n] = __builtin_amdgcn_mfma_f32_16x16x32_bf16(a[m], b[n], acc[m][n], 0, 0, 0);
        __builtin_amdgcn_s_setprio(0);
        __builtin_amdgcn_sched_barrier(0);
        __builtin_amdgcn_s_barrier();          // B: all waves consumed tile t
    }
#else
    STAGE(0, 0);
    __syncthreads();
#pragma unroll
    for (int t = 0; t < nt; ++t) {
        const int cur = t & 1;
        if (t + 1 < nt) STAGE(cur ^ 1, (t + 1) << 5);
        short8v a[4], b[4];
#pragma unroll
        for (int m = 0; m < 4; ++m) a[m] = *(const short8v*)&sm.st.As[cur][(frow_a + m * 16) * 32 + fks];
#pragma unroll
        for (int n = 0; n < 4; ++n) b[n] = *(const short8v*)&sm.st.Bs[cur][(frow_b + n * 16) * 32 + fks];
#pragma unroll
        for (int m = 0; m < 4; ++m)
#pragma unroll
            for (int n = 0; n < 4; ++n)
                acc[m][n] = __builtin_amdgcn_mfma_f32_16x16x32_bf16(a[m], b[n], acc[m][n], 0, 0, 0);
        if (t + 1 < nt) __syncthreads();
    }
#endif
#undef STAGE

    // ---- epilogue: LDS-staged coalesced bf16 stores ----
    __syncthreads();   // staging ring dead; overlay output buffer
    short* yb = (short*)Yb + (size_t)row0 * ldyb + col0;
    // (T14) ACC: issue old-OUT reads NOW; the pack phase below hides latency.
    short8v oldv[8];
    if (ACC) {
#pragma unroll
        for (int it = 0; it < 8; ++it) {
            int r = (tid >> 4) + it * 32;
            int c8 = (tid & 15) * 8;
            oldv[it] = *(const short8v*)(yb + (size_t)r * ldyb + c8);
        }
    }
    int lr = (lane >> 4) * 4;
    int lc = lane & 15;
#pragma unroll
    for (int n = 0; n < 4; ++n) {
        int c = wc * 64 + n * 16 + lc;
        float bv = BIAS ? bias[col0 + c] : 0.0f;
#pragma unroll
        for (int m = 0; m < 4; ++m) {
#pragma unroll
            for (int j = 0; j < 4; ++j) {
                float v = acc[m][n][j] + bv;
                if (GELU) v = gelu_f(v);
                sm.obf[wr * 64 + m * 16 + lr + j][c] = bf16s(v);
            }
        }
    }
    __syncthreads();
#pragma unroll
    for (int it = 0; it < 8; ++it) {
        int r = (tid >> 4) + it * 32;
        int c8 = (tid & 15) * 8;
        short8v v = *(const short8v*)&sm.obf[r][c8];
        short* yp = yb + (size_t)r * ldyb + c8;
        if (ACC) {
#pragma unroll
            for (int e = 0; e < 8; ++e) v[e] = bf16s(bf2f(v[e]) + bf2f(oldv[it][e]));
        }
        *(short8v*)yp = v;
    }
}

// ---------------- MFMA attention, barrier-free, XCD-swizzled ----------------
__global__ __launch_bounds__(256) void attn_mfma_kernel(
    const __hip_bfloat16* __restrict__ qkv,
    const float* __restrict__ biasT,
    __hip_bfloat16* __restrict__ o,
    int T, float scale, int nwin) {
    __shared__ __align__(16) short Vt[4][32][72];   // [wave][d][kt]  (V transposed)
    __shared__ __align__(16) short Pl[4][64][40];   // [wave][r][half-K cols]
    const int tid = threadIdx.x, lane = tid & 63, wv = tid >> 6;
    int p, hg;
    {
        int L = blockIdx.x;
        if (nwin & 7) { hg = L % 3; p = L / 3; }
        else { int r = L & 7, pos = L >> 3; hg = pos % 3; p = (pos / 3) * 8 + r; }
    }
    const int h = hg * 4 + wv;
    const short* q_base = (const short*)qkv + (size_t)p * T * N3;

    const int fr = lane & 15;
    const int fk = (lane >> 4) * 8;
    const int lg = lane >> 4;
    const int lc = lane & 15;

    short8v aq[4], bk[4];
#pragma unroll
    for (int m = 0; m < 4; ++m) {
        const short* qp = q_base + (size_t)(m * 16 + fr) * N3 + h * 32 + fk;
        aq[m] = *(const short8v*)qp;
        bk[m] = *(const short8v*)(qp + 384);
    }

    for (int ch = lane; ch < T * 4; ch += 64) {
        int t = ch >> 2, cq = ch & 3;
        short8v v8 = *(const short8v*)(q_base + (size_t)t * N3 + 768 + h * 32 + cq * 8);
#pragma unroll
        for (int e = 0; e < 8; ++e) Vt[wv][cq * 8 + e][t] = v8[e];
    }
    for (int idx = lane; idx < (64 - T) * 32; idx += 64) {
        int t = T + (idx >> 5), d = idx & 31;
        Vt[wv][d][t] = 0;
    }

    f32x4 acc[4][4] = {};
#pragma unroll
    for (int m = 0; m < 4; ++m)
#pragma unroll
        for (int n = 0; n < 4; ++n)
            acc[m][n] = __builtin_amdgcn_mfma_f32_16x16x32_bf16(aq[m], bk[n], acc[m][n], 0, 0, 0);

    const float* bh = biasT ? (biasT + (size_t)h * 4096) : nullptr;
    float p2[4][4], p3[4][4];
#pragma unroll
    for (int m = 0; m < 4; ++m) {
#pragma unroll
        for (int j = 0; j < 4; ++j) {
            int r = m * 16 + lg * 4 + j;
            float v[4];
            if (bh) {
                float4 bv4 = *(const float4*)(bh + r * 64 + lc * 4);
#pragma unroll
                for (int n = 0; n < 4; ++n) v[n] = acc[m][n][j] * scale + ((const float*)&bv4)[n];
            } else {
#pragma unroll
                for (int n = 0; n < 4; ++n) v[n] = acc[m][n][j] * scale;
            }
#pragma unroll
            for (int n = 0; n < 4; ++n)
                if (n * 16 + lc >= T) v[n] = -1e30f;
            float mx = fmaxf(fmaxf(v[0], v[1]), fmaxf(v[2], v[3]));
#pragma unroll
            for (int off = 1; off < 16; off <<= 1) mx = fmaxf(mx, __shfl_xor(mx, off));
            float s = 0.f;
#pragma unroll
            for (int n = 0; n < 4; ++n) { v[n] = __expf(v[n] - mx); s += v[n]; }
#pragma unroll
            for (int off = 1; off < 16; off <<= 1) s += __shfl_xor(s, off);
            float inv = 1.0f / s;
            Pl[wv][r][lc]      = bf16s(v[0] * inv);
            Pl[wv][r][16 + lc] = bf16s(v[1] * inv);
            p2[m][j] = v[2] * inv;
            p3[m][j] = v[3] * inv;
        }
    }

    f32x4 oacc[4][2] = {};
    {
        short8v ap[4], bv[2];
#pragma unroll
        for (int m = 0; m < 4; ++m) ap[m] = *(const short8v*)&Pl[wv][m * 16 + fr][fk];
#pragma unroll
        for (int n = 0; n < 2; ++n) bv[n] = *(const short8v*)&Vt[wv][n * 16 + fr][fk];
#pragma unroll
        for (int m = 0; m < 4; ++m)
#pragma unroll
            for (int n = 0; n < 2; ++n)
                oacc[m][n] = __builtin_amdgcn_mfma_f32_16x16x32_bf16(ap[m], bv[n], oacc[m][n], 0, 0, 0);
    }
#pragma unroll
    for (int m = 0; m < 4; ++m)
#pragma unroll
        for (int j = 0; j < 4; ++j) {
            int r = m * 16 + lg * 4 + j;
            Pl[wv][r][lc]      = bf16s(p2[m][j]);
            Pl[wv][r][16 + lc] = bf16s(p3[m][j]);
        }
    {
        short8v ap[4], bv[2];
#pragma unroll
        for (int m = 0; m < 4; ++m) ap[m] = *(const short8v*)&Pl[wv][m * 16 + fr][fk];
#pragma unroll
        for (int n = 0; n < 2; ++n) bv[n] = *(const short8v*)&Vt[wv][n * 16 + fr][32 + fk];
#pragma unroll
        for (int m = 0; m < 4; ++m)
#pragma unroll
            for (int n = 0; n < 2; ++n)
                oacc[m][n] = __builtin_amdgcn_mfma_f32_16x16x32_bf16(ap[m], bv[n], oacc[m][n], 0, 0, 0);
    }

    short* ob = (short*)o;
#pragma unroll
    for (int m = 0; m < 4; ++m)
#pragma unroll
        for (int j = 0; j < 4; ++j) {
            int r = m * 16 + lg * 4 + j;
            if (r < T) {
#pragma unroll
                for (int n = 0; n < 2; ++n)
                    ob[((size_t)p * T + r) * CC + h * 32 + n * 16 + lc] = bf16s(oacc[m][n][j]);
            }
        }
}

// ---------------- host ----------------
extern "C" void kernel_launch(void* const* d_in, const int* in_sizes, int n_in,
                              void* d_out, int out_size, void* d_ws, size_t ws_size,
                              hipStream_t stream) {
    const float* cls_in   = (const float*)d_in[0];
    const float* patch_in = (const float*)d_in[1];
    const float* qkv_w    = (const float*)d_in[2];
    const float* qkv_b    = (const float*)d_in[3];
    const float* proj_w   = (const float*)d_in[4];
    const float* proj_b   = (const float*)d_in[5];
    const float* rel_pos  = (const float*)d_in[6];
    const float* ln0w = (const float*)d_in[7];
    const float* ln0b = (const float*)d_in[8];
    const float* ln1w = (const float*)d_in[9];
    const float* ln1b = (const float*)d_in[10];
    const float* ln2w = (const float*)d_in[11];
    const float* ln2b = (const float*)d_in[12];
    const float* w1 = (const float*)d_in[13];
    const float* b1 = (const float*)d_in[14];
    const float* w2 = (const float*)d_in[15];
    const float* b2 = (const float*)d_in[16];

    float* WS = (float*)d_ws;
    size_t avail = ws_size / 4;

    // bf16 residual stream: 2048*50*384 bf16 = 19,660,800 f32 slots
    const size_t OUT_FB = 19660800;
    const size_t WB_F   = 1769472;           // bf16 weights (f32 slots)
    const size_t BT_F   = 49152;             // bias table 12*64*64 fp32
    __hip_bfloat16* OUTB = (__hip_bfloat16*)WS;
    __hip_bfloat16* WB = (__hip_bfloat16*)(WS + OUT_FB);
    __hip_bfloat16* qwb = WB;                                   // 2*1152*384
    __hip_bfloat16* pwb = WB + 884736;                          // 2*384*384
    __hip_bfloat16* w1b = WB + 1179648;                         // 2*1536*384
    __hip_bfloat16* w2b = WB + 2359296;                         // 2*384*1536
    float* biasTbuf = WS + OUT_FB + WB_F;

    // cw = 2048 (R16: halves stage-B/C dispatch count). cw*NTT % 256 == 0.
    int cw = 2048;
    while (cw > 128 && OUT_FB + WB_F + BT_F + (size_t)cw * 48000 > avail) cw >>= 1;
    float* fbase = WS + OUT_FB + WB_F + BT_F;
    __hip_bfloat16* Xb = (__hip_bfloat16*)fbase;
    __hip_bfloat16* Qb = (__hip_bfloat16*)(fbase + (size_t)cw * 9600);
    __hip_bfloat16* Hb = Qb;   // MLP hidden reuses Qb region
    const float scale = 0.17677669529663687f;

    f2bf_kernel<<<dim3((884736 / 4 + 255) / 256), dim3(256), 0, stream>>>(qkv_w, qwb, 884736);
    f2bf_kernel<<<dim3((294912 / 4 + 255) / 256), dim3(256), 0, stream>>>(proj_w, pwb, 294912);
    f2bf_kernel<<<dim3((1179648 / 4 + 255) / 256), dim3(256), 0, stream>>>(w1, w1b, 1179648);
    f2bf_kernel<<<dim3((1179648 / 4 + 255) / 256), dim3(256), 0, stream>>>(w2, w2b, 1179648);

    pack_cls_kernel<<<dim3(BB * 6), dim3(256), 0, stream>>>(cls_in, OUTB);
    pack_patch_kernel<<<dim3(BB * 56 * 6), dim3(256), 0, stream>>>(patch_in, OUTB);

    for (int i = 0; i < NBB; ++i) {
        const __hip_bfloat16* qw = qwb + (size_t)i * N3 * CC;
        const float* qb = qkv_b + (size_t)i * N3;
        const __hip_bfloat16* pw = pwb + (size_t)i * CC * CC;
        const float* pb = proj_b + (size_t)i * CC;
        const float* rp = rel_pos + (size_t)i * NHH * 169;
        const __hip_bfloat16* w1i = w1b + (size_t)i * HIDD * CC;
        const float* b1i = b1 + (size_t)i * HIDD;
        const __hip_bfloat16* w2i = w2b + (size_t)i * CC * HIDD;
        const float* b2i = b2 + (size_t)i * CC;

        bias_precompute_kernel<<<dim3(NHH), dim3(256), 0, stream>>>(rp, biasTbuf);

        // ---- stage A: cls attention across 64 windows of each image (T=64) ----
        ln_kernel<<<dim3(2048 / 4), dim3(256), 0, stream>>>(OUTB, LDOUT, ln0w + i * CC, ln0b + i * CC, Xb, CC, 2048);
        gemm_bf16_kernel<1, 0, 0, CC><<<dim3((N3 / 128) * (2048 / 256)), dim3(512), 0, stream>>>(
            Xb, CC, qw, qb, Qb, N3, 2048, N3, N3 / 128);
        attn_mfma_kernel<<<dim3(BB * 3), dim3(256), 0, stream>>>(Qb, nullptr, Xb, 64, scale, BB);
        gemm_bf16_kernel<1, 0, 1, CC><<<dim3((CC / 128) * (2048 / 256)), dim3(512), 0, stream>>>(
            Xb, CC, pw, pb, OUTB, LDOUT, 2048, CC, CC / 128);

        // ---- stage B: windowed attention with rel-pos bias (T=50) ----
        for (int w0 = 0; w0 < NWW; w0 += cw) {
            __hip_bfloat16* outc = OUTB + (size_t)w0 * LDOUT;
            int Mr = cw * NTT;
            ln_kernel<<<dim3(Mr / 4), dim3(256), 0, stream>>>(outc, CC, ln1w + i * CC, ln1b + i * CC, Xb, CC, Mr);
            gemm_bf16_kernel<1, 0, 0, CC><<<dim3((N3 / 128) * (Mr / 256)), dim3(512), 0, stream>>>(
                Xb, CC, qw, qb, Qb, N3, Mr, N3, N3 / 128);
            attn_mfma_kernel<<<dim3(cw * 3), dim3(256), 0, stream>>>(Qb, biasTbuf, Xb, NTT, scale, cw);
            gemm_bf16_kernel<1, 0, 1, CC><<<dim3((CC / 128) * (Mr / 256)), dim3(512), 0, stream>>>(
                Xb, CC, pw, pb, outc, CC, Mr, CC, CC / 128);
        }

        // ---- stage C: MLP ----
        for (int w0 = 0; w0 < NWW; w0 += cw) {
            __hip_bfloat16* outc = OUTB + (size_t)w0 * LDOUT;
            int Mr = cw * NTT;
            ln_kernel<<<dim3(Mr / 4), dim3(256), 0, stream>>>(outc, CC, ln2w + i * CC, ln2b + i * CC, Xb, CC, Mr);
            gemm_bf16_kernel<1, 1, 0, CC><<<dim3((HIDD / 128) * (Mr / 256)), dim3(512), 0, stream>>>(
                Xb, CC, w1i, b1i, Hb, HIDD, Mr, HIDD, HIDD / 128);
            gemm_bf16_kernel<1, 0, 1, HIDD><<<dim3((CC / 128) * (Mr / 256)), dim3(512), 0, stream>>>(
                Hb, HIDD, w2i, b2i, outc, CC, Mr, CC, CC / 128);
        }
    }

    unpack_cls_kernel<<<dim3(BB * 6), dim3(256), 0, stream>>>(OUTB, (float*)d_out);
    unpack_patch_kernel<<<dim3(BB * 56 * 6), dim3(256), 0, stream>>>(OUTB, (float*)d_out + 786432);
}